// Round 1
// baseline (679.588 us; speedup 1.0000x reference)
//
#include <hip/hip_runtime.h>
#include <hip/hip_bf16.h>
#include <float.h>

#define N_ORB 1024
#define KSEL 32
#define LEAK 0.01f
#define EPSV 1e-20f

__device__ __forceinline__ float leaky(float x) { return x >= 0.0f ? x : LEAK * x; }

__device__ __forceinline__ float wave_max64(float v) {
#pragma unroll
  for (int o = 32; o; o >>= 1) v = fmaxf(v, __shfl_xor(v, o, 64));
  return v;
}
__device__ __forceinline__ float wave_sum64(float v) {
#pragma unroll
  for (int o = 32; o; o >>= 1) v += __shfl_xor(v, o, 64);
  return v;
}

// Runs the 32-step successive-softmax chain on s[16] (blocked layout:
// element j = lane*16 + i), then selects top-32 of khot with jax top_k
// tie semantics (stable: equal value -> lower index). Returns per-lane
// 16-bit selection mask; writes the k-th selected global index into
// `sel` of lane k (k<32).
__device__ unsigned run_chain_topk(float s[16], int lane, int& sel) {
  float khot[16];
#pragma unroll
  for (int i = 0; i < 16; ++i) khot[i] = 0.0f;

  for (int it = 0; it < KSEL; ++it) {
    float lm = -FLT_MAX;
#pragma unroll
    for (int i = 0; i < 16; ++i) lm = fmaxf(lm, s[i]);
    float m = wave_max64(lm);
    float e[16];
    float ls = 0.0f;
#pragma unroll
    for (int i = 0; i < 16; ++i) { e[i] = __expf(s[i] - m); ls += e[i]; }
    float Z = wave_sum64(ls);
    float rZ = 1.0f / Z;
#pragma unroll
    for (int i = 0; i < 16; ++i) {
      float p = e[i] * rZ;
      khot[i] += p;
      s[i] += __logf(fmaxf(1.0f - p, EPSV));
    }
  }

  unsigned mask = 0;
  sel = 0;
  for (int k = 0; k < KSEL; ++k) {
    float bv = -FLT_MAX;
    int bi = 0x7fffffff;
#pragma unroll
    for (int i = 0; i < 16; ++i) {
      if (khot[i] > bv) { bv = khot[i]; bi = (lane << 4) | i; }
    }
#pragma unroll
    for (int o = 32; o; o >>= 1) {
      float ov = __shfl_xor(bv, o, 64);
      int oi = __shfl_xor(bi, o, 64);
      if (ov > bv || (ov == bv && oi < bi)) { bv = ov; bi = oi; }
    }
    if ((bi >> 4) == lane) { khot[bi & 15] = -FLT_MAX; mask |= 1u << (bi & 15); }
    if (k == lane) sel = bi;
  }
  return mask;
}

// One block, runs once: computes
//   ws[0..1023]    = alpha const logits = MLP_a(baseline_a) + baseline_a
//   ws[1024..1151] = hpreB[n] = sum_j baseline_b[j] * W1b[j,n]  (first-layer
//                    contribution of the row-constant base_b input)
extern "C" __global__ void pcfs_precompute(
    const float* __restrict__ ba, const float* __restrict__ W1a,
    const float* __restrict__ b1a, const float* __restrict__ W2a,
    const float* __restrict__ b2a, const float* __restrict__ W3a,
    const float* __restrict__ b3a, const float* __restrict__ bb,
    const float* __restrict__ W1b, float* __restrict__ ws) {
  __shared__ float h1[128];
  __shared__ float h2[64];
  const int t = threadIdx.x;
  if (t < 128) {
    float acc = b1a[t];
#pragma unroll 8
    for (int j = 0; j < N_ORB; ++j) acc += ba[j] * W1a[j * 128 + t];
    h1[t] = leaky(acc);
  } else {
    const int n = t - 128;
    float acc = 0.0f;
#pragma unroll 8
    for (int j = 0; j < N_ORB; ++j) acc += bb[j] * W1b[j * 128 + n];
    ws[N_ORB + n] = acc;
  }
  __syncthreads();
  if (t < 64) {
    float acc = b2a[t];
#pragma unroll 8
    for (int n = 0; n < 128; ++n) acc += h1[n] * W2a[n * 64 + t];
    h2[t] = leaky(acc);
  }
  __syncthreads();
#pragma unroll
  for (int i = 0; i < 4; ++i) {
    const int j = t + 256 * i;
    float acc = b3a[j];
#pragma unroll 8
    for (int m = 0; m < 64; ++m) acc += h2[m] * W3a[m * N_ORB + j];
    ws[j] = acc + ba[j];  // + base_a
  }
}

// One wave per batch row. 256 threads = 4 independent waves, no barriers.
extern "C" __global__ void __launch_bounds__(256, 4) pcfs_sampler(
    const float* __restrict__ ws, const float* __restrict__ Wc,
    const float* __restrict__ bc, const float* __restrict__ W1b,
    const float* __restrict__ b1b, const float* __restrict__ W2b,
    const float* __restrict__ b2b, const float* __restrict__ W3b,
    const float* __restrict__ b3b, const float* __restrict__ bb,
    const float* __restrict__ g_alpha, const float* __restrict__ g_beta,
    float* __restrict__ out, int B) {
  const int wave = threadIdx.x >> 6;
  const int lane = threadIdx.x & 63;
  const int row = blockIdx.x * 4 + wave;
  if (row >= B) return;

  // ---- alpha chain: scores0 = const_logits + gumbel ----
  float s[16];
  {
    const float4* c4 = (const float4*)ws;
    const float4* g4 = (const float4*)(g_alpha + (size_t)row * N_ORB);
#pragma unroll
    for (int q = 0; q < 4; ++q) {
      float4 c = c4[lane * 4 + q];
      float4 g = g4[lane * 4 + q];
      s[4 * q + 0] = c.x + g.x;
      s[4 * q + 1] = c.y + g.y;
      s[4 * q + 2] = c.z + g.z;
      s[4 * q + 3] = c.w + g.w;
    }
  }
  int sel;
  const unsigned amask = run_chain_topk(s, lane, sel);

  // write alpha half (hard config: exact 0/1)
  {
    float4* o4 = (float4*)(out + (size_t)row * (2 * N_ORB));
#pragma unroll
    for (int q = 0; q < 4; ++q) {
      float4 o;
      o.x = ((amask >> (4 * q + 0)) & 1) ? 1.0f : 0.0f;
      o.y = ((amask >> (4 * q + 1)) & 1) ? 1.0f : 0.0f;
      o.z = ((amask >> (4 * q + 2)) & 1) ? 1.0f : 0.0f;
      o.w = ((amask >> (4 * q + 3)) & 1) ? 1.0f : 0.0f;
      o4[lane * 4 + q] = o;
    }
  }

  // ---- ctx = alpha_config @ Wc + bc  (gather-sum of 32 rows of Wc) ----
  float ctxv = (lane < 32) ? bc[lane] : 0.0f;
  for (int k = 0; k < KSEL; ++k) {
    const int idx = __shfl(sel, k, 64);
    if (lane < 32) ctxv += Wc[idx * 32 + lane];
  }

  // ---- h1 = leaky(base_b@W1b[0:1024] + ctx@W1b[1024:1056] + b1b) ----
  float h1a = b1b[lane] + ws[N_ORB + lane];
  float h1b = b1b[lane + 64] + ws[N_ORB + lane + 64];
#pragma unroll 4
  for (int c = 0; c < 32; ++c) {
    const float cv = __shfl(ctxv, c, 64);
    const float* wr = W1b + (size_t)(N_ORB + c) * 128;
    h1a += cv * wr[lane];
    h1b += cv * wr[lane + 64];
  }
  h1a = leaky(h1a);
  h1b = leaky(h1b);

  // ---- h2 = leaky(h1 @ W2b + b2b) ----
  float h2v = b2b[lane];
#pragma unroll 4
  for (int n = 0; n < 64; ++n) {
    const float hv = __shfl(h1a, n, 64);
    h2v += hv * W2b[n * 64 + lane];
  }
#pragma unroll 4
  for (int n = 0; n < 64; ++n) {
    const float hv = __shfl(h1b, n, 64);
    h2v += hv * W2b[(n + 64) * 64 + lane];
  }
  h2v = leaky(h2v);

  // ---- beta logits = h2 @ W3b + b3b (+ base_b), then + gumbel ----
  float acc[16];
  {
    const float4* b4 = (const float4*)b3b;
#pragma unroll
    for (int q = 0; q < 4; ++q) {
      float4 b = b4[lane * 4 + q];
      acc[4 * q + 0] = b.x;
      acc[4 * q + 1] = b.y;
      acc[4 * q + 2] = b.z;
      acc[4 * q + 3] = b.w;
    }
  }
  for (int m = 0; m < 64; ++m) {
    const float hm = __shfl(h2v, m, 64);
    const float4* w4 = (const float4*)(W3b + m * N_ORB);
#pragma unroll
    for (int q = 0; q < 4; ++q) {
      float4 w = w4[lane * 4 + q];
      acc[4 * q + 0] += hm * w.x;
      acc[4 * q + 1] += hm * w.y;
      acc[4 * q + 2] += hm * w.z;
      acc[4 * q + 3] += hm * w.w;
    }
  }
  {
    const float4* bb4 = (const float4*)bb;
    const float4* g4 = (const float4*)(g_beta + (size_t)row * N_ORB);
#pragma unroll
    for (int q = 0; q < 4; ++q) {
      float4 b = bb4[lane * 4 + q];
      float4 g = g4[lane * 4 + q];
      s[4 * q + 0] = acc[4 * q + 0] + b.x + g.x;
      s[4 * q + 1] = acc[4 * q + 1] + b.y + g.y;
      s[4 * q + 2] = acc[4 * q + 2] + b.z + g.z;
      s[4 * q + 3] = acc[4 * q + 3] + b.w + g.w;
    }
  }
  int selb;
  const unsigned bmask = run_chain_topk(s, lane, selb);

  {
    float4* o4 = (float4*)(out + (size_t)row * (2 * N_ORB) + N_ORB);
#pragma unroll
    for (int q = 0; q < 4; ++q) {
      float4 o;
      o.x = ((bmask >> (4 * q + 0)) & 1) ? 1.0f : 0.0f;
      o.y = ((bmask >> (4 * q + 1)) & 1) ? 1.0f : 0.0f;
      o.z = ((bmask >> (4 * q + 2)) & 1) ? 1.0f : 0.0f;
      o.w = ((bmask >> (4 * q + 3)) & 1) ? 1.0f : 0.0f;
      o4[lane * 4 + q] = o;
    }
  }
}

extern "C" void kernel_launch(void* const* d_in, const int* in_sizes, int n_in,
                              void* d_out, int out_size, void* d_ws, size_t ws_size,
                              hipStream_t stream) {
  const float* ba  = (const float*)d_in[0];
  const float* W1a = (const float*)d_in[1];
  const float* b1a = (const float*)d_in[2];
  const float* W2a = (const float*)d_in[3];
  const float* b2a = (const float*)d_in[4];
  const float* W3a = (const float*)d_in[5];
  const float* b3a = (const float*)d_in[6];
  const float* bb  = (const float*)d_in[7];
  const float* Wc  = (const float*)d_in[8];
  const float* bc  = (const float*)d_in[9];
  const float* W1b = (const float*)d_in[10];
  const float* b1b = (const float*)d_in[11];
  const float* W2b = (const float*)d_in[12];
  const float* b2b = (const float*)d_in[13];
  const float* W3b = (const float*)d_in[14];
  const float* b3b = (const float*)d_in[15];
  const float* ga  = (const float*)d_in[16];
  const float* gbt = (const float*)d_in[17];
  const int B = in_sizes[16] / N_ORB;
  float* ws = (float*)d_ws;

  hipLaunchKernelGGL(pcfs_precompute, dim3(1), dim3(256), 0, stream,
                     ba, W1a, b1a, W2a, b2a, W3a, b3a, bb, W1b, ws);
  hipLaunchKernelGGL(pcfs_sampler, dim3((B + 3) / 4), dim3(256), 0, stream,
                     ws, Wc, bc, W1b, b1b, W2b, b2b, W3b, b3b, bb,
                     ga, gbt, (float*)d_out, B);
}

// Round 2
// 518.772 us; speedup vs baseline: 1.3100x; 1.3100x over previous
//
#include <hip/hip_runtime.h>
#include <hip/hip_bf16.h>
#include <float.h>

#define N_ORB 1024
#define KSEL 32
#define LEAK 0.01f
#define EPSV 1e-20f
#define LOG2E 1.4426950408889634f

__device__ __forceinline__ float leaky(float x) { return x >= 0.0f ? x : LEAK * x; }

// ds_swizzle xor-butterfly step within 32-lane halves (imm must be ICE -> template)
template <int IMM>
__device__ __forceinline__ float swz(float v) {
  return __int_as_float(__builtin_amdgcn_ds_swizzle(__float_as_int(v), IMM));
}

// full 64-lane sum: xor 1,2,4,8,16 via ds_swizzle + cross-half via bpermute
__device__ __forceinline__ float wave_sum64(float v) {
  v += swz<0x041F>(v);
  v += swz<0x081F>(v);
  v += swz<0x101F>(v);
  v += swz<0x201F>(v);
  v += swz<0x401F>(v);
  v += __shfl_xor(v, 32, 64);
  return v;
}
__device__ __forceinline__ float wave_max64(float v) {
  v = fmaxf(v, swz<0x041F>(v));
  v = fmaxf(v, swz<0x081F>(v));
  v = fmaxf(v, swz<0x101F>(v));
  v = fmaxf(v, swz<0x201F>(v));
  v = fmaxf(v, swz<0x401F>(v));
  v = fmaxf(v, __shfl_xor(v, 32, 64));
  return v;
}

// Successive-softmax chain in LOG2 domain (u = s * log2e), stale-max guard
// recomputed every 4 iterations, then top-32 selection with jax top_k tie
// semantics (equal value -> lower index). Returns per-lane 16-bit mask;
// lane k (k<32) gets the k-th selected global index in `sel`.
__device__ unsigned run_chain_topk(float u[16], int lane, int& sel) {
  float khot[16];
#pragma unroll
  for (int i = 0; i < 16; ++i) khot[i] = 0.0f;

  float m = 0.0f;
  for (int it = 0; it < KSEL; ++it) {
    if ((it & 3) == 0) {  // stale-max refresh: u only decreases, so m stays valid
      float lm = -FLT_MAX;
#pragma unroll
      for (int i = 0; i < 16; ++i) lm = fmaxf(lm, u[i]);
      m = wave_max64(lm);
    }
    float e[16];
    float ls = 0.0f;
#pragma unroll
    for (int i = 0; i < 16; ++i) { e[i] = __builtin_amdgcn_exp2f(u[i] - m); ls += e[i]; }
    float Z = wave_sum64(ls);
    Z = fmaxf(Z, 1e-35f);  // paranoia: avoid inf*0 if everything underflows
    float r0 = __builtin_amdgcn_rcpf(Z);
    float rZ = __builtin_fmaf(__builtin_fmaf(-Z, r0, 1.0f), r0, r0);  // 1 Newton step
#pragma unroll
    for (int i = 0; i < 16; ++i) {
      float p = e[i] * rZ;
      khot[i] += p;
      u[i] += __builtin_amdgcn_logf(fmaxf(1.0f - p, EPSV));  // v_log IS log2
    }
  }

  unsigned mask = 0;
  sel = 0;
  for (int k = 0; k < KSEL; ++k) {
    float bv = -FLT_MAX;
    int bi = 0x7fffffff;
#pragma unroll
    for (int i = 0; i < 16; ++i) {
      if (khot[i] > bv) { bv = khot[i]; bi = (lane << 4) | i; }
    }
#pragma unroll
    for (int o = 32; o; o >>= 1) {
      float ov = __shfl_xor(bv, o, 64);
      int oi = __shfl_xor(bi, o, 64);
      if (ov > bv || (ov == bv && oi < bi)) { bv = ov; bi = oi; }
    }
    if ((bi >> 4) == lane) { khot[bi & 15] = -FLT_MAX; mask |= 1u << (bi & 15); }
    if (k == lane) sel = bi;
  }
  return mask;
}

// One block, runs once: computes
//   ws[0..1023]    = alpha const logits = MLP_a(baseline_a) + baseline_a
//   ws[1024..1151] = hpreB[n] = sum_j baseline_b[j] * W1b[j,n]
extern "C" __global__ void pcfs_precompute(
    const float* __restrict__ ba, const float* __restrict__ W1a,
    const float* __restrict__ b1a, const float* __restrict__ W2a,
    const float* __restrict__ b2a, const float* __restrict__ W3a,
    const float* __restrict__ b3a, const float* __restrict__ bb,
    const float* __restrict__ W1b, float* __restrict__ ws) {
  __shared__ float h1[128];
  __shared__ float h2[64];
  const int t = threadIdx.x;
  if (t < 128) {
    float acc = b1a[t];
#pragma unroll 16
    for (int j = 0; j < N_ORB; ++j) acc += ba[j] * W1a[j * 128 + t];
    h1[t] = leaky(acc);
  } else {
    const int n = t - 128;
    float acc = 0.0f;
#pragma unroll 16
    for (int j = 0; j < N_ORB; ++j) acc += bb[j] * W1b[j * 128 + n];
    ws[N_ORB + n] = acc;
  }
  __syncthreads();
  if (t < 64) {
    float acc = b2a[t];
#pragma unroll 16
    for (int n = 0; n < 128; ++n) acc += h1[n] * W2a[n * 64 + t];
    h2[t] = leaky(acc);
  }
  __syncthreads();
#pragma unroll
  for (int i = 0; i < 4; ++i) {
    const int j = t + 256 * i;
    float acc = b3a[j];
#pragma unroll 16
    for (int m = 0; m < 64; ++m) acc += h2[m] * W3a[m * N_ORB + j];
    ws[j] = acc + ba[j];  // + base_a
  }
}

// One wave per batch row. 256 threads = 4 independent waves, no barriers.
extern "C" __global__ void __launch_bounds__(256, 4) pcfs_sampler(
    const float* __restrict__ ws, const float* __restrict__ Wc,
    const float* __restrict__ bc, const float* __restrict__ W1b,
    const float* __restrict__ b1b, const float* __restrict__ W2b,
    const float* __restrict__ b2b, const float* __restrict__ W3b,
    const float* __restrict__ b3b, const float* __restrict__ bb,
    const float* __restrict__ g_alpha, const float* __restrict__ g_beta,
    float* __restrict__ out, int B) {
  const int wave = threadIdx.x >> 6;
  const int lane = threadIdx.x & 63;
  const int row = blockIdx.x * 4 + wave;
  if (row >= B) return;

  // ---- alpha chain: u = (const_logits + gumbel) * log2e ----
  float u[16];
  {
    const float4* c4 = (const float4*)ws;
    const float4* g4 = (const float4*)(g_alpha + (size_t)row * N_ORB);
#pragma unroll
    for (int q = 0; q < 4; ++q) {
      float4 c = c4[lane * 4 + q];
      float4 g = g4[lane * 4 + q];
      u[4 * q + 0] = (c.x + g.x) * LOG2E;
      u[4 * q + 1] = (c.y + g.y) * LOG2E;
      u[4 * q + 2] = (c.z + g.z) * LOG2E;
      u[4 * q + 3] = (c.w + g.w) * LOG2E;
    }
  }
  int sel;
  const unsigned amask = run_chain_topk(u, lane, sel);

  // write alpha half (hard config: exact 0/1)
  {
    float4* o4 = (float4*)(out + (size_t)row * (2 * N_ORB));
#pragma unroll
    for (int q = 0; q < 4; ++q) {
      float4 o;
      o.x = ((amask >> (4 * q + 0)) & 1) ? 1.0f : 0.0f;
      o.y = ((amask >> (4 * q + 1)) & 1) ? 1.0f : 0.0f;
      o.z = ((amask >> (4 * q + 2)) & 1) ? 1.0f : 0.0f;
      o.w = ((amask >> (4 * q + 3)) & 1) ? 1.0f : 0.0f;
      o4[lane * 4 + q] = o;
    }
  }

  // ---- ctx = alpha_config @ Wc + bc  (gather-sum of 32 rows of Wc) ----
  float ctxv = (lane < 32) ? bc[lane] : 0.0f;
  for (int k = 0; k < KSEL; ++k) {
    const int idx = __shfl(sel, k, 64);
    if (lane < 32) ctxv += Wc[idx * 32 + lane];
  }

  // ---- h1 = leaky(base_b@W1b[0:1024] + ctx@W1b[1024:1056] + b1b) ----
  float h1a = b1b[lane] + ws[N_ORB + lane];
  float h1b = b1b[lane + 64] + ws[N_ORB + lane + 64];
#pragma unroll 4
  for (int c = 0; c < 32; ++c) {
    const float cv = __shfl(ctxv, c, 64);
    const float* wr = W1b + (size_t)(N_ORB + c) * 128;
    h1a += cv * wr[lane];
    h1b += cv * wr[lane + 64];
  }
  h1a = leaky(h1a);
  h1b = leaky(h1b);

  // ---- h2 = leaky(h1 @ W2b + b2b) ----
  float h2v = b2b[lane];
#pragma unroll 4
  for (int n = 0; n < 64; ++n) {
    const float hv = __shfl(h1a, n, 64);
    h2v += hv * W2b[n * 64 + lane];
  }
#pragma unroll 4
  for (int n = 0; n < 64; ++n) {
    const float hv = __shfl(h1b, n, 64);
    h2v += hv * W2b[(n + 64) * 64 + lane];
  }
  h2v = leaky(h2v);

  // ---- beta logits = h2 @ W3b + b3b (+ base_b), then + gumbel, -> log2 dom ----
  float acc[16];
  {
    const float4* b4 = (const float4*)b3b;
#pragma unroll
    for (int q = 0; q < 4; ++q) {
      float4 b = b4[lane * 4 + q];
      acc[4 * q + 0] = b.x;
      acc[4 * q + 1] = b.y;
      acc[4 * q + 2] = b.z;
      acc[4 * q + 3] = b.w;
    }
  }
  for (int m = 0; m < 64; ++m) {
    const float hm = __shfl(h2v, m, 64);
    const float4* w4 = (const float4*)(W3b + m * N_ORB);
#pragma unroll
    for (int q = 0; q < 4; ++q) {
      float4 w = w4[lane * 4 + q];
      acc[4 * q + 0] += hm * w.x;
      acc[4 * q + 1] += hm * w.y;
      acc[4 * q + 2] += hm * w.z;
      acc[4 * q + 3] += hm * w.w;
    }
  }
  {
    const float4* bb4 = (const float4*)bb;
    const float4* g4 = (const float4*)(g_beta + (size_t)row * N_ORB);
#pragma unroll
    for (int q = 0; q < 4; ++q) {
      float4 b = bb4[lane * 4 + q];
      float4 g = g4[lane * 4 + q];
      u[4 * q + 0] = (acc[4 * q + 0] + b.x + g.x) * LOG2E;
      u[4 * q + 1] = (acc[4 * q + 1] + b.y + g.y) * LOG2E;
      u[4 * q + 2] = (acc[4 * q + 2] + b.z + g.z) * LOG2E;
      u[4 * q + 3] = (acc[4 * q + 3] + b.w + g.w) * LOG2E;
    }
  }
  int selb;
  const unsigned bmask = run_chain_topk(u, lane, selb);

  {
    float4* o4 = (float4*)(out + (size_t)row * (2 * N_ORB) + N_ORB);
#pragma unroll
    for (int q = 0; q < 4; ++q) {
      float4 o;
      o.x = ((bmask >> (4 * q + 0)) & 1) ? 1.0f : 0.0f;
      o.y = ((bmask >> (4 * q + 1)) & 1) ? 1.0f : 0.0f;
      o.z = ((bmask >> (4 * q + 2)) & 1) ? 1.0f : 0.0f;
      o.w = ((bmask >> (4 * q + 3)) & 1) ? 1.0f : 0.0f;
      o4[lane * 4 + q] = o;
    }
  }
}

extern "C" void kernel_launch(void* const* d_in, const int* in_sizes, int n_in,
                              void* d_out, int out_size, void* d_ws, size_t ws_size,
                              hipStream_t stream) {
  const float* ba  = (const float*)d_in[0];
  const float* W1a = (const float*)d_in[1];
  const float* b1a = (const float*)d_in[2];
  const float* W2a = (const float*)d_in[3];
  const float* b2a = (const float*)d_in[4];
  const float* W3a = (const float*)d_in[5];
  const float* b3a = (const float*)d_in[6];
  const float* bb  = (const float*)d_in[7];
  const float* Wc  = (const float*)d_in[8];
  const float* bc  = (const float*)d_in[9];
  const float* W1b = (const float*)d_in[10];
  const float* b1b = (const float*)d_in[11];
  const float* W2b = (const float*)d_in[12];
  const float* b2b = (const float*)d_in[13];
  const float* W3b = (const float*)d_in[14];
  const float* b3b = (const float*)d_in[15];
  const float* ga  = (const float*)d_in[16];
  const float* gbt = (const float*)d_in[17];
  const int B = in_sizes[16] / N_ORB;
  float* ws = (float*)d_ws;

  hipLaunchKernelGGL(pcfs_precompute, dim3(1), dim3(256), 0, stream,
                     ba, W1a, b1a, W2a, b2a, W3a, b3a, bb, W1b, ws);
  hipLaunchKernelGGL(pcfs_sampler, dim3((B + 3) / 4), dim3(256), 0, stream,
                     ws, Wc, bc, W1b, b1b, W2b, b2b, W3b, b3b, bb,
                     ga, gbt, (float*)d_out, B);
}

// Round 3
// 418.293 us; speedup vs baseline: 1.6247x; 1.2402x over previous
//
#include <hip/hip_runtime.h>
#include <hip/hip_bf16.h>
#include <float.h>

#define N_ORB 1024
#define KSEL 32
#define LEAK 0.01f
#define EPSV 1e-20f
#define LOG2E 1.4426950408889634f

__device__ __forceinline__ float leaky(float x) { return x >= 0.0f ? x : LEAK * x; }

// ---- DPP helpers (VALU-pipe cross-lane; no LDS latency) ----
// row_shr:n = 0x110|n, row_bcast15 = 0x142, row_bcast31 = 0x143
template <int CTRL>
__device__ __forceinline__ float dpp_zero(float v) {  // invalid lanes read 0
  return __int_as_float(
      __builtin_amdgcn_update_dpp(0, __float_as_int(v), CTRL, 0xF, 0xF, true));
}
template <int CTRL>
__device__ __forceinline__ float dpp_self_f(float v) {  // invalid lanes keep self
  return __int_as_float(__builtin_amdgcn_update_dpp(
      __float_as_int(v), __float_as_int(v), CTRL, 0xF, 0xF, false));
}
template <int CTRL>
__device__ __forceinline__ int dpp_self_i(int v) {
  return __builtin_amdgcn_update_dpp(v, v, CTRL, 0xF, 0xF, false);
}
__device__ __forceinline__ float rdlane(float v, int l) {
  return __int_as_float(__builtin_amdgcn_readlane(__float_as_int(v), l));
}

// full 64-lane sum, result broadcast (via readlane 63 -> SGPR)
__device__ __forceinline__ float wave_sum64_dpp(float v) {
  v += dpp_zero<0x111>(v);
  v += dpp_zero<0x112>(v);
  v += dpp_zero<0x114>(v);
  v += dpp_zero<0x118>(v);
  v += dpp_zero<0x142>(v);  // bcast15
  v += dpp_zero<0x143>(v);  // bcast31
  return rdlane(v, 63);
}

// one (value,index) argmax combine step; prefers larger value, then lower index
template <int CTRL>
__device__ __forceinline__ void amax_step(float& bv, int& bi) {
  float ov = dpp_self_f<CTRL>(bv);
  int oi = dpp_self_i<CTRL>(bi);
  bool take = (ov > bv) || (ov == bv && oi < bi);
  bv = take ? ov : bv;
  bi = take ? oi : bi;
}

// Successive-softmax chain in LOG2 domain, NO max-shift (args bounded),
// then top-32 with jax top_k tie semantics (equal value -> lower index).
// Returns per-lane 16-bit mask; lane k (k<32) gets k-th selected index in sel.
__device__ unsigned run_chain_topk(float u[16], int lane, int& sel) {
  float khot[16];
#pragma unroll
  for (int i = 0; i < 16; ++i) khot[i] = 0.0f;

  for (int it = 0; it < KSEL; ++it) {
    float e[16];
#pragma unroll
    for (int i = 0; i < 16; ++i) e[i] = __builtin_amdgcn_exp2f(u[i]);
    // depth-4 pairwise tree for the lane-local sum
    float t0 = e[0] + e[1], t1 = e[2] + e[3], t2 = e[4] + e[5], t3 = e[6] + e[7];
    float t4 = e[8] + e[9], t5 = e[10] + e[11], t6 = e[12] + e[13], t7 = e[14] + e[15];
    t0 += t1; t2 += t3; t4 += t5; t6 += t7;
    t0 += t2; t4 += t6;
    float Z = wave_sum64_dpp(t0 + t4);
    Z = fmaxf(Z, 1e-30f);  // guard: never 0
    float r0 = __builtin_amdgcn_rcpf(Z);
    float rZ = __builtin_fmaf(__builtin_fmaf(-Z, r0, 1.0f), r0, r0);
#pragma unroll
    for (int i = 0; i < 16; ++i) {
      khot[i] = __builtin_fmaf(e[i], rZ, khot[i]);
      float om = __builtin_fmaf(-e[i], rZ, 1.0f);  // 1 - p, single fma
      u[i] += __builtin_amdgcn_logf(fmaxf(om, EPSV));  // v_log IS log2
    }
  }

  unsigned mask = 0;
  sel = 0;
  for (int k = 0; k < KSEL; ++k) {
    // lane-local argmax: depth-4 tree, ties keep lower slot
    float va[8];
    int sa[8];
#pragma unroll
    for (int i = 0; i < 8; ++i) {
      bool tk = khot[2 * i + 1] > khot[2 * i];
      va[i] = tk ? khot[2 * i + 1] : khot[2 * i];
      sa[i] = tk ? 2 * i + 1 : 2 * i;
    }
#pragma unroll
    for (int i = 0; i < 4; ++i) {
      bool tk = va[2 * i + 1] > va[2 * i];
      va[i] = tk ? va[2 * i + 1] : va[2 * i];
      sa[i] = tk ? sa[2 * i + 1] : sa[2 * i];
    }
    bool tk0 = va[1] > va[0];
    bool tk1 = va[3] > va[2];
    float vx = tk0 ? va[1] : va[0], vy = tk1 ? va[3] : va[2];
    int sx = tk0 ? sa[1] : sa[0], sy = tk1 ? sa[3] : sa[2];
    bool tk2 = vy > vx;
    float bv = tk2 ? vy : vx;
    int bi = (lane << 4) | (tk2 ? sy : sx);

    // wave argmax via DPP (VALU pipe), winner lands in lane 63
    amax_step<0x111>(bv, bi);
    amax_step<0x112>(bv, bi);
    amax_step<0x114>(bv, bi);
    amax_step<0x118>(bv, bi);
    amax_step<0x142>(bv, bi);
    amax_step<0x143>(bv, bi);
    const int wbi = __builtin_amdgcn_readlane(bi, 63);  // uniform winner
    const int wl = wbi >> 4;
    const int slot = wbi & 15;
    const bool mine = (lane == wl);
    if (mine) mask |= 1u << slot;
#pragma unroll
    for (int i = 0; i < 16; ++i)
      if (i == slot) khot[i] = mine ? -FLT_MAX : khot[i];  // slot is uniform
    if (lane == k) sel = wbi;
  }
  return mask;
}

// ---- precompute, stage 1 (grid 256): the two length-1024 dot layers ----
// block b<128:   h1[b]   -> ws[1152+b]   (leaky(dot(ba,W1a[:,b]) + b1a[b]))
// block b>=128:  hpreB[n]-> ws[1024+n]   (dot(bb,W1b[:,n]), raw)
extern "C" __global__ void pcfs_pre1(const float* __restrict__ ba,
                                     const float* __restrict__ W1a,
                                     const float* __restrict__ b1a,
                                     const float* __restrict__ bb,
                                     const float* __restrict__ W1b,
                                     float* __restrict__ ws) {
  const int b = blockIdx.x;
  const int t = threadIdx.x;
  float acc = 0.0f;
  if (b < 128) {
#pragma unroll
    for (int j = t; j < N_ORB; j += 256) acc += ba[j] * W1a[j * 128 + b];
  } else {
    const int n = b - 128;
#pragma unroll
    for (int j = t; j < N_ORB; j += 256) acc += bb[j] * W1b[j * 128 + n];
  }
  __shared__ float red[4];
  float wsum = wave_sum64_dpp(acc);
  if ((t & 63) == 0) red[t >> 6] = wsum;
  __syncthreads();
  if (t == 0) {
    float tot = red[0] + red[1] + red[2] + red[3];
    if (b < 128)
      ws[1152 + b] = leaky(tot + b1a[b]);
    else
      ws[N_ORB + (b - 128)] = tot;
  }
}

// ---- precompute, stage 2 (1 block x 1024): h2 + alpha const logits ----
extern "C" __global__ void pcfs_pre2(const float* __restrict__ ba,
                                     const float* __restrict__ W2a,
                                     const float* __restrict__ b2a,
                                     const float* __restrict__ W3a,
                                     const float* __restrict__ b3a,
                                     float* __restrict__ ws) {
  __shared__ float h1[128];
  __shared__ float h2[64];
  const int t = threadIdx.x;
  if (t < 128) h1[t] = ws[1152 + t];
  __syncthreads();
  if (t < 64) {
    float acc = b2a[t];
#pragma unroll 8
    for (int n = 0; n < 128; ++n) acc += h1[n] * W2a[n * 64 + t];
    h2[t] = leaky(acc);
  }
  __syncthreads();
  float acc = b3a[t];
#pragma unroll 8
  for (int m = 0; m < 64; ++m) acc += h2[m] * W3a[m * N_ORB + t];
  ws[t] = acc + ba[t];  // + base_a
}

// One wave per batch row. 256 threads = 4 independent waves, no barriers.
extern "C" __global__ void __launch_bounds__(256, 4) pcfs_sampler(
    const float* __restrict__ ws, const float* __restrict__ Wc,
    const float* __restrict__ bc, const float* __restrict__ W1b,
    const float* __restrict__ b1b, const float* __restrict__ W2b,
    const float* __restrict__ b2b, const float* __restrict__ W3b,
    const float* __restrict__ b3b, const float* __restrict__ bb,
    const float* __restrict__ g_alpha, const float* __restrict__ g_beta,
    float* __restrict__ out, int B) {
  const int wave = threadIdx.x >> 6;
  const int lane = threadIdx.x & 63;
  const int row = blockIdx.x * 4 + wave;
  if (row >= B) return;

  // ---- alpha chain: u = (const_logits + gumbel) * log2e ----
  float u[16];
  {
    const float4* c4 = (const float4*)ws;
    const float4* g4 = (const float4*)(g_alpha + (size_t)row * N_ORB);
#pragma unroll
    for (int q = 0; q < 4; ++q) {
      float4 c = c4[lane * 4 + q];
      float4 g = g4[lane * 4 + q];
      u[4 * q + 0] = (c.x + g.x) * LOG2E;
      u[4 * q + 1] = (c.y + g.y) * LOG2E;
      u[4 * q + 2] = (c.z + g.z) * LOG2E;
      u[4 * q + 3] = (c.w + g.w) * LOG2E;
    }
  }
  int sel;
  const unsigned amask = run_chain_topk(u, lane, sel);

  // write alpha half (hard config: exact 0/1)
  {
    float4* o4 = (float4*)(out + (size_t)row * (2 * N_ORB));
#pragma unroll
    for (int q = 0; q < 4; ++q) {
      float4 o;
      o.x = ((amask >> (4 * q + 0)) & 1) ? 1.0f : 0.0f;
      o.y = ((amask >> (4 * q + 1)) & 1) ? 1.0f : 0.0f;
      o.z = ((amask >> (4 * q + 2)) & 1) ? 1.0f : 0.0f;
      o.w = ((amask >> (4 * q + 3)) & 1) ? 1.0f : 0.0f;
      o4[lane * 4 + q] = o;
    }
  }

  // ---- ctx = alpha_config @ Wc + bc (gather-sum of 32 rows of Wc) ----
  float ctxv = bc[lane & 31];
#pragma unroll 4
  for (int k = 0; k < KSEL; ++k) {
    const int idx = __builtin_amdgcn_readlane(sel, k);  // uniform
    ctxv += Wc[idx * 32 + (lane & 31)];
  }

  // ---- h1 = leaky(base_b@W1b[0:1024] + ctx@W1b[1024:1056] + b1b) ----
  float h1a = b1b[lane] + ws[N_ORB + lane];
  float h1b = b1b[lane + 64] + ws[N_ORB + lane + 64];
#pragma unroll 4
  for (int c = 0; c < 32; ++c) {
    const float cv = rdlane(ctxv, c);
    const float* wr = W1b + (size_t)(N_ORB + c) * 128;
    h1a += cv * wr[lane];
    h1b += cv * wr[lane + 64];
  }
  h1a = leaky(h1a);
  h1b = leaky(h1b);

  // ---- h2 = leaky(h1 @ W2b + b2b) ----
  float h2v = b2b[lane];
#pragma unroll 4
  for (int n = 0; n < 64; ++n) {
    const float hv = rdlane(h1a, n);
    h2v += hv * W2b[n * 64 + lane];
  }
#pragma unroll 4
  for (int n = 0; n < 64; ++n) {
    const float hv = rdlane(h1b, n);
    h2v += hv * W2b[(n + 64) * 64 + lane];
  }
  h2v = leaky(h2v);

  // ---- beta logits = h2 @ W3b + b3b (+ base_b), + gumbel, -> log2 dom ----
  float acc[16];
  {
    const float4* b4 = (const float4*)b3b;
#pragma unroll
    for (int q = 0; q < 4; ++q) {
      float4 b = b4[lane * 4 + q];
      acc[4 * q + 0] = b.x;
      acc[4 * q + 1] = b.y;
      acc[4 * q + 2] = b.z;
      acc[4 * q + 3] = b.w;
    }
  }
  for (int m = 0; m < 64; ++m) {
    const float hm = rdlane(h2v, m);
    const float4* w4 = (const float4*)(W3b + m * N_ORB);
#pragma unroll
    for (int q = 0; q < 4; ++q) {
      float4 w = w4[lane * 4 + q];
      acc[4 * q + 0] += hm * w.x;
      acc[4 * q + 1] += hm * w.y;
      acc[4 * q + 2] += hm * w.z;
      acc[4 * q + 3] += hm * w.w;
    }
  }
  {
    const float4* bb4 = (const float4*)bb;
    const float4* g4 = (const float4*)(g_beta + (size_t)row * N_ORB);
#pragma unroll
    for (int q = 0; q < 4; ++q) {
      float4 b = bb4[lane * 4 + q];
      float4 g = g4[lane * 4 + q];
      u[4 * q + 0] = (acc[4 * q + 0] + b.x + g.x) * LOG2E;
      u[4 * q + 1] = (acc[4 * q + 1] + b.y + g.y) * LOG2E;
      u[4 * q + 2] = (acc[4 * q + 2] + b.z + g.z) * LOG2E;
      u[4 * q + 3] = (acc[4 * q + 3] + b.w + g.w) * LOG2E;
    }
  }
  int selb;
  const unsigned bmask = run_chain_topk(u, lane, selb);

  {
    float4* o4 = (float4*)(out + (size_t)row * (2 * N_ORB) + N_ORB);
#pragma unroll
    for (int q = 0; q < 4; ++q) {
      float4 o;
      o.x = ((bmask >> (4 * q + 0)) & 1) ? 1.0f : 0.0f;
      o.y = ((bmask >> (4 * q + 1)) & 1) ? 1.0f : 0.0f;
      o.z = ((bmask >> (4 * q + 2)) & 1) ? 1.0f : 0.0f;
      o.w = ((bmask >> (4 * q + 3)) & 1) ? 1.0f : 0.0f;
      o4[lane * 4 + q] = o;
    }
  }
}

extern "C" void kernel_launch(void* const* d_in, const int* in_sizes, int n_in,
                              void* d_out, int out_size, void* d_ws, size_t ws_size,
                              hipStream_t stream) {
  const float* ba  = (const float*)d_in[0];
  const float* W1a = (const float*)d_in[1];
  const float* b1a = (const float*)d_in[2];
  const float* W2a = (const float*)d_in[3];
  const float* b2a = (const float*)d_in[4];
  const float* W3a = (const float*)d_in[5];
  const float* b3a = (const float*)d_in[6];
  const float* bb  = (const float*)d_in[7];
  const float* Wc  = (const float*)d_in[8];
  const float* bc  = (const float*)d_in[9];
  const float* W1b = (const float*)d_in[10];
  const float* b1b = (const float*)d_in[11];
  const float* W2b = (const float*)d_in[12];
  const float* b2b = (const float*)d_in[13];
  const float* W3b = (const float*)d_in[14];
  const float* b3b = (const float*)d_in[15];
  const float* ga  = (const float*)d_in[16];
  const float* gbt = (const float*)d_in[17];
  const int B = in_sizes[16] / N_ORB;
  float* ws = (float*)d_ws;

  hipLaunchKernelGGL(pcfs_pre1, dim3(256), dim3(256), 0, stream,
                     ba, W1a, b1a, bb, W1b, ws);
  hipLaunchKernelGGL(pcfs_pre2, dim3(1), dim3(1024), 0, stream,
                     ba, W2a, b2a, W3a, b3a, ws);
  hipLaunchKernelGGL(pcfs_sampler, dim3((B + 3) / 4), dim3(256), 0, stream,
                     ws, Wc, bc, W1b, b1b, W2b, b2b, W3b, b3b, bb,
                     ga, gbt, (float*)d_out, B);
}

// Round 4
// 375.714 us; speedup vs baseline: 1.8088x; 1.1133x over previous
//
#include <hip/hip_runtime.h>
#include <hip/hip_bf16.h>
#include <float.h>

#define N_ORB 1024
#define KSEL 32
#define LEAK 0.01f
#define EPSV 1e-20f
#define LOG2E 1.4426950408889634f

typedef float f32x2 __attribute__((ext_vector_type(2)));

__device__ __forceinline__ float leaky(float x) { return x >= 0.0f ? x : LEAK * x; }

// ---- DPP helpers (VALU-pipe cross-lane) ----
template <int CTRL>
__device__ __forceinline__ float dpp_zero(float v) {  // invalid lanes read 0
  return __int_as_float(
      __builtin_amdgcn_update_dpp(0, __float_as_int(v), CTRL, 0xF, 0xF, true));
}
template <int CTRL>
__device__ __forceinline__ float dpp_self_f(float v) {  // invalid lanes keep self
  return __int_as_float(__builtin_amdgcn_update_dpp(
      __float_as_int(v), __float_as_int(v), CTRL, 0xF, 0xF, false));
}
template <int CTRL>
__device__ __forceinline__ int dpp_self_i(int v) {
  return __builtin_amdgcn_update_dpp(v, v, CTRL, 0xF, 0xF, false);
}
__device__ __forceinline__ float rdlane(float v, int l) {
  return __int_as_float(__builtin_amdgcn_readlane(__float_as_int(v), l));
}

// full 64-lane sum, result uniform (readlane 63 -> SGPR)
__device__ __forceinline__ float wave_sum64_dpp(float v) {
  v += dpp_zero<0x111>(v);
  v += dpp_zero<0x112>(v);
  v += dpp_zero<0x114>(v);
  v += dpp_zero<0x118>(v);
  v += dpp_zero<0x142>(v);  // bcast15
  v += dpp_zero<0x143>(v);  // bcast31
  return rdlane(v, 63);
}

// one (value,index) argmax combine; prefers larger value, then lower index
template <int CTRL>
__device__ __forceinline__ void amax_step(float& bv, int& bi) {
  float ov = dpp_self_f<CTRL>(bv);
  int oi = dpp_self_i<CTRL>(bi);
  bool take = (ov > bv) || (ov == bv && oi < bi);
  bv = take ? ov : bv;
  bi = take ? oi : bi;
}

// Successive-softmax chain, MULTIPLICATIVE form: w tracks exp(s).
//   p_i = w_i / Z;  khot_i += p_i;  w_i *= max(1-p_i, EPS)
// (exactly the reference recurrence; softmax shift-invariance makes w/Z == softmax(s)).
// Then top-32 of khot with jax top_k tie semantics (equal value -> lower index).
// w/khot live as packed float2 (v_pk_* on CDNA). Element (lane<<4)|(2i+half).
__device__ unsigned run_chain_topk(f32x2 w[8], int lane, int& sel) {
  f32x2 kh[8];
#pragma unroll
  for (int i = 0; i < 8; ++i) kh[i] = (f32x2)(0.0f, 0.0f);

  const f32x2 onev = (f32x2)(1.0f, 1.0f);
  const f32x2 epsv = (f32x2)(EPSV, EPSV);
  for (int it = 0; it < KSEL; ++it) {
    f32x2 s01 = w[0] + w[1], s23 = w[2] + w[3];
    f32x2 s45 = w[4] + w[5], s67 = w[6] + w[7];
    s01 += s23;
    s45 += s67;
    s01 += s45;
    float Z = wave_sum64_dpp(s01.x + s01.y);
    Z = fmaxf(Z, 1e-30f);
    float r0 = __builtin_amdgcn_rcpf(Z);
    float rZs = __builtin_fmaf(__builtin_fmaf(-Z, r0, 1.0f), r0, r0);
    const f32x2 rZ = (f32x2)(rZs, rZs);
#pragma unroll
    for (int i = 0; i < 8; ++i) {
      kh[i] = __builtin_elementwise_fma(w[i], rZ, kh[i]);
      f32x2 om = __builtin_elementwise_fma(-w[i], rZ, onev);
      om = __builtin_elementwise_max(om, epsv);
      w[i] = w[i] * om;
    }
  }

  unsigned mask = 0;
  sel = 0;
  for (int k = 0; k < KSEL; ++k) {
    // lane-local argmax tree (ties keep lower slot); khot >= 0, cleared = -1
    float va[8];
    int sa[8];
#pragma unroll
    for (int i = 0; i < 8; ++i) {
      bool tk = kh[i].y > kh[i].x;
      va[i] = tk ? kh[i].y : kh[i].x;
      sa[i] = tk ? 2 * i + 1 : 2 * i;
    }
#pragma unroll
    for (int i = 0; i < 4; ++i) {
      bool tk = va[2 * i + 1] > va[2 * i];
      va[i] = tk ? va[2 * i + 1] : va[2 * i];
      sa[i] = tk ? sa[2 * i + 1] : sa[2 * i];
    }
    bool tk0 = va[1] > va[0];
    bool tk1 = va[3] > va[2];
    float vx = tk0 ? va[1] : va[0], vy = tk1 ? va[3] : va[2];
    int sx = tk0 ? sa[1] : sa[0], sy = tk1 ? sa[3] : sa[2];
    bool tk2 = vy > vx;
    float bv = tk2 ? vy : vx;
    int bi = (lane << 4) | (tk2 ? sy : sx);

    amax_step<0x111>(bv, bi);
    amax_step<0x112>(bv, bi);
    amax_step<0x114>(bv, bi);
    amax_step<0x118>(bv, bi);
    amax_step<0x142>(bv, bi);
    amax_step<0x143>(bv, bi);
    const int wbi = __builtin_amdgcn_readlane(bi, 63);  // uniform winner
    const int slot = wbi & 15;                          // uniform
    const bool mine = (lane == (wbi >> 4));
    if (mine) mask |= 1u << slot;
    const int hs = slot >> 1;
    const bool hi = slot & 1;
#pragma unroll
    for (int i = 0; i < 8; ++i) {
      if (i == hs) {  // uniform condition
        if (hi)
          kh[i].y = mine ? -1.0f : kh[i].y;
        else
          kh[i].x = mine ? -1.0f : kh[i].x;
      }
    }
    if (lane == k) sel = wbi;
  }
  return mask;
}

// ---- precompute, stage 1 (grid 256): the two length-1024 dot layers ----
extern "C" __global__ void pcfs_pre1(const float* __restrict__ ba,
                                     const float* __restrict__ W1a,
                                     const float* __restrict__ b1a,
                                     const float* __restrict__ bb,
                                     const float* __restrict__ W1b,
                                     float* __restrict__ ws) {
  const int b = blockIdx.x;
  const int t = threadIdx.x;
  float acc = 0.0f;
  if (b < 128) {
#pragma unroll
    for (int j = t; j < N_ORB; j += 256) acc += ba[j] * W1a[j * 128 + b];
  } else {
    const int n = b - 128;
#pragma unroll
    for (int j = t; j < N_ORB; j += 256) acc += bb[j] * W1b[j * 128 + n];
  }
  __shared__ float red[4];
  float wsum = wave_sum64_dpp(acc);
  if ((t & 63) == 0) red[t >> 6] = wsum;
  __syncthreads();
  if (t == 0) {
    float tot = red[0] + red[1] + red[2] + red[3];
    if (b < 128)
      ws[1152 + b] = leaky(tot + b1a[b]);
    else
      ws[N_ORB + (b - 128)] = tot;
  }
}

// ---- precompute, stage 2 (1 block x 1024): h2 + alpha const logits ----
extern "C" __global__ void pcfs_pre2(const float* __restrict__ ba,
                                     const float* __restrict__ W2a,
                                     const float* __restrict__ b2a,
                                     const float* __restrict__ W3a,
                                     const float* __restrict__ b3a,
                                     float* __restrict__ ws) {
  __shared__ float h1[128];
  __shared__ float h2[64];
  const int t = threadIdx.x;
  if (t < 128) h1[t] = ws[1152 + t];
  __syncthreads();
  if (t < 64) {
    float acc = b2a[t];
#pragma unroll 8
    for (int n = 0; n < 128; ++n) acc += h1[n] * W2a[n * 64 + t];
    h2[t] = leaky(acc);
  }
  __syncthreads();
  float acc = b3a[t];
#pragma unroll 8
  for (int m = 0; m < 64; ++m) acc += h2[m] * W3a[m * N_ORB + t];
  ws[t] = acc + ba[t];  // + base_a
}

// One wave per batch row. 256 threads = 4 independent waves, no barriers.
extern "C" __global__ void __launch_bounds__(256, 4) pcfs_sampler(
    const float* __restrict__ ws, const float* __restrict__ Wc,
    const float* __restrict__ bc, const float* __restrict__ W1b,
    const float* __restrict__ b1b, const float* __restrict__ W2b,
    const float* __restrict__ b2b, const float* __restrict__ W3b,
    const float* __restrict__ b3b, const float* __restrict__ bb,
    const float* __restrict__ g_alpha, const float* __restrict__ g_beta,
    float* __restrict__ out, int B) {
  const int wave = threadIdx.x >> 6;
  const int lane = threadIdx.x & 63;
  const int row = blockIdx.x * 4 + wave;
  if (row >= B) return;

  // ---- alpha chain: w = exp2((const_logits + gumbel) * log2e) ----
  f32x2 w[8];
  {
    const float4* c4 = (const float4*)ws;
    const float4* g4 = (const float4*)(g_alpha + (size_t)row * N_ORB);
#pragma unroll
    for (int q = 0; q < 4; ++q) {
      float4 c = c4[lane * 4 + q];
      float4 g = g4[lane * 4 + q];
      w[2 * q + 0].x = __builtin_amdgcn_exp2f((c.x + g.x) * LOG2E);
      w[2 * q + 0].y = __builtin_amdgcn_exp2f((c.y + g.y) * LOG2E);
      w[2 * q + 1].x = __builtin_amdgcn_exp2f((c.z + g.z) * LOG2E);
      w[2 * q + 1].y = __builtin_amdgcn_exp2f((c.w + g.w) * LOG2E);
    }
  }
  int sel;
  const unsigned amask = run_chain_topk(w, lane, sel);

  // write alpha half (hard config: exact 0/1)
  {
    float4* o4 = (float4*)(out + (size_t)row * (2 * N_ORB));
#pragma unroll
    for (int q = 0; q < 4; ++q) {
      float4 o;
      o.x = ((amask >> (4 * q + 0)) & 1) ? 1.0f : 0.0f;
      o.y = ((amask >> (4 * q + 1)) & 1) ? 1.0f : 0.0f;
      o.z = ((amask >> (4 * q + 2)) & 1) ? 1.0f : 0.0f;
      o.w = ((amask >> (4 * q + 3)) & 1) ? 1.0f : 0.0f;
      o4[lane * 4 + q] = o;
    }
  }

  // ---- ctx = alpha_config @ Wc + bc (gather-sum of 32 rows of Wc) ----
  float ctxv = bc[lane & 31];
#pragma unroll 4
  for (int k = 0; k < KSEL; ++k) {
    const int idx = __builtin_amdgcn_readlane(sel, k);  // uniform
    ctxv += Wc[idx * 32 + (lane & 31)];
  }

  // ---- h1 = leaky(base_b@W1b[0:1024] + ctx@W1b[1024:1056] + b1b) ----
  float h1a = b1b[lane] + ws[N_ORB + lane];
  float h1b = b1b[lane + 64] + ws[N_ORB + lane + 64];
#pragma unroll 4
  for (int c = 0; c < 32; ++c) {
    const float cv = rdlane(ctxv, c);
    const float* wr = W1b + (size_t)(N_ORB + c) * 128;
    h1a += cv * wr[lane];
    h1b += cv * wr[lane + 64];
  }
  h1a = leaky(h1a);
  h1b = leaky(h1b);

  // ---- h2 = leaky(h1 @ W2b + b2b) ----
  float h2v = b2b[lane];
#pragma unroll 4
  for (int n = 0; n < 64; ++n) {
    const float hv = rdlane(h1a, n);
    h2v += hv * W2b[n * 64 + lane];
  }
#pragma unroll 4
  for (int n = 0; n < 64; ++n) {
    const float hv = rdlane(h1b, n);
    h2v += hv * W2b[(n + 64) * 64 + lane];
  }
  h2v = leaky(h2v);

  // ---- beta logits = h2 @ W3b + b3b (+ base_b), + gumbel -> w ----
  float acc[16];
  {
    const float4* b4 = (const float4*)b3b;
#pragma unroll
    for (int q = 0; q < 4; ++q) {
      float4 b = b4[lane * 4 + q];
      acc[4 * q + 0] = b.x;
      acc[4 * q + 1] = b.y;
      acc[4 * q + 2] = b.z;
      acc[4 * q + 3] = b.w;
    }
  }
  for (int m = 0; m < 64; ++m) {
    const float hm = rdlane(h2v, m);
    const float4* w4 = (const float4*)(W3b + m * N_ORB);
#pragma unroll
    for (int q = 0; q < 4; ++q) {
      float4 wv = w4[lane * 4 + q];
      acc[4 * q + 0] += hm * wv.x;
      acc[4 * q + 1] += hm * wv.y;
      acc[4 * q + 2] += hm * wv.z;
      acc[4 * q + 3] += hm * wv.w;
    }
  }
  {
    const float4* bb4 = (const float4*)bb;
    const float4* g4 = (const float4*)(g_beta + (size_t)row * N_ORB);
#pragma unroll
    for (int q = 0; q < 4; ++q) {
      float4 b = bb4[lane * 4 + q];
      float4 g = g4[lane * 4 + q];
      w[2 * q + 0].x = __builtin_amdgcn_exp2f((acc[4 * q + 0] + b.x + g.x) * LOG2E);
      w[2 * q + 0].y = __builtin_amdgcn_exp2f((acc[4 * q + 1] + b.y + g.y) * LOG2E);
      w[2 * q + 1].x = __builtin_amdgcn_exp2f((acc[4 * q + 2] + b.z + g.z) * LOG2E);
      w[2 * q + 1].y = __builtin_amdgcn_exp2f((acc[4 * q + 3] + b.w + g.w) * LOG2E);
    }
  }
  int selb;
  const unsigned bmask = run_chain_topk(w, lane, selb);

  {
    float4* o4 = (float4*)(out + (size_t)row * (2 * N_ORB) + N_ORB);
#pragma unroll
    for (int q = 0; q < 4; ++q) {
      float4 o;
      o.x = ((bmask >> (4 * q + 0)) & 1) ? 1.0f : 0.0f;
      o.y = ((bmask >> (4 * q + 1)) & 1) ? 1.0f : 0.0f;
      o.z = ((bmask >> (4 * q + 2)) & 1) ? 1.0f : 0.0f;
      o.w = ((bmask >> (4 * q + 3)) & 1) ? 1.0f : 0.0f;
      o4[lane * 4 + q] = o;
    }
  }
}

extern "C" void kernel_launch(void* const* d_in, const int* in_sizes, int n_in,
                              void* d_out, int out_size, void* d_ws, size_t ws_size,
                              hipStream_t stream) {
  const float* ba  = (const float*)d_in[0];
  const float* W1a = (const float*)d_in[1];
  const float* b1a = (const float*)d_in[2];
  const float* W2a = (const float*)d_in[3];
  const float* b2a = (const float*)d_in[4];
  const float* W3a = (const float*)d_in[5];
  const float* b3a = (const float*)d_in[6];
  const float* bb  = (const float*)d_in[7];
  const float* Wc  = (const float*)d_in[8];
  const float* bc  = (const float*)d_in[9];
  const float* W1b = (const float*)d_in[10];
  const float* b1b = (const float*)d_in[11];
  const float* W2b = (const float*)d_in[12];
  const float* b2b = (const float*)d_in[13];
  const float* W3b = (const float*)d_in[14];
  const float* b3b = (const float*)d_in[15];
  const float* ga  = (const float*)d_in[16];
  const float* gbt = (const float*)d_in[17];
  const int B = in_sizes[16] / N_ORB;
  float* ws = (float*)d_ws;

  hipLaunchKernelGGL(pcfs_pre1, dim3(256), dim3(256), 0, stream,
                     ba, W1a, b1a, bb, W1b, ws);
  hipLaunchKernelGGL(pcfs_pre2, dim3(1), dim3(1024), 0, stream,
                     ba, W2a, b2a, W3a, b3a, ws);
  hipLaunchKernelGGL(pcfs_sampler, dim3((B + 3) / 4), dim3(256), 0, stream,
                     ws, Wc, bc, W1b, b1b, W2b, b2b, W3b, b3b, bb,
                     ga, gbt, (float*)d_out, B);
}

// Round 6
// 365.617 us; speedup vs baseline: 1.8587x; 1.0276x over previous
//
#include <hip/hip_runtime.h>
#include <hip/hip_bf16.h>
#include <float.h>

#define N_ORB 1024
#define KSEL 32
#define LEAK 0.01f
#define EPSV 1e-20f
#define LOG2E 1.4426950408889634f

typedef float f32x2 __attribute__((ext_vector_type(2)));
// NOTE: never write (f32x2)(a, b) — in C++ that's a comma-expr cast that
// SPLATS b. Use f32x2{a, b}.

__device__ __forceinline__ float leaky(float x) { return x >= 0.0f ? x : LEAK * x; }

// ---- DPP helpers ----
template <int CTRL, int RM>
__device__ __forceinline__ int dpp0_i(int v) {  // masked-off rows contribute 0
  return __builtin_amdgcn_update_dpp(0, v, CTRL, RM, 0xF, true);
}
template <int CTRL>
__device__ __forceinline__ float dpp_zero(float v) {
  return __int_as_float(
      __builtin_amdgcn_update_dpp(0, __float_as_int(v), CTRL, 0xF, 0xF, true));
}
template <int CTRL>
__device__ __forceinline__ float dpp_self_f(float v) {  // invalid lanes keep self
  return __int_as_float(__builtin_amdgcn_update_dpp(
      __float_as_int(v), __float_as_int(v), CTRL, 0xF, 0xF, false));
}
template <int CTRL>
__device__ __forceinline__ int dpp_self_i(int v) {
  return __builtin_amdgcn_update_dpp(v, v, CTRL, 0xF, 0xF, false);
}
__device__ __forceinline__ float rdlane(float v, int l) {
  return __int_as_float(__builtin_amdgcn_readlane(__float_as_int(v), l));
}

// full 64-lane float sum, uniform result
__device__ __forceinline__ float wave_sum64_dpp(float v) {
  v += dpp_zero<0x111>(v);
  v += dpp_zero<0x112>(v);
  v += dpp_zero<0x114>(v);
  v += dpp_zero<0x118>(v);
  v += dpp_zero<0x142>(v);
  v += dpp_zero<0x143>(v);
  return rdlane(v, 63);
}
// full 64-lane int sum, uniform result
__device__ __forceinline__ int wave_isum64(int v) {
  v += dpp0_i<0x111, 0xF>(v);
  v += dpp0_i<0x112, 0xF>(v);
  v += dpp0_i<0x114, 0xF>(v);
  v += dpp0_i<0x118, 0xF>(v);
  v += dpp0_i<0x142, 0xF>(v);
  v += dpp0_i<0x143, 0xF>(v);
  return __builtin_amdgcn_readlane(v, 63);
}
// 64-lane inclusive prefix sum (int), per-lane result
__device__ __forceinline__ int wave_iscan64(int v) {
  v += dpp0_i<0x111, 0xF>(v);
  v += dpp0_i<0x112, 0xF>(v);
  v += dpp0_i<0x114, 0xF>(v);
  v += dpp0_i<0x118, 0xF>(v);
  v += dpp0_i<0x142, 0xA>(v);  // bcast15 into rows 1,3
  v += dpp0_i<0x143, 0xC>(v);  // bcast31 into rows 2,3
  return v;
}

// one (value,index) argmax combine; prefers larger value, then lower index
template <int CTRL>
__device__ __forceinline__ void amax_step(float& bv, int& bi) {
  float ov = dpp_self_f<CTRL>(bv);
  int oi = dpp_self_i<CTRL>(bi);
  bool take = (ov > bv) || (ov == bv && oi < bi);
  bv = take ? ov : bv;
  bi = take ? oi : bi;
}

// Successive-softmax chain, multiplicative form (w tracks exp(s)); khot out.
__device__ void run_chain(f32x2 w[8], f32x2 kh[8]) {
#pragma unroll
  for (int i = 0; i < 8; ++i) kh[i] = f32x2{0.0f, 0.0f};
  const f32x2 onev = f32x2{1.0f, 1.0f};
  const f32x2 epsv = f32x2{EPSV, EPSV};
  for (int it = 0; it < KSEL; ++it) {
    f32x2 s01 = w[0] + w[1], s23 = w[2] + w[3];
    f32x2 s45 = w[4] + w[5], s67 = w[6] + w[7];
    s01 += s23;
    s45 += s67;
    s01 += s45;
    float Z = wave_sum64_dpp(s01.x + s01.y);
    Z = fmaxf(Z, 1e-30f);
    float r0 = __builtin_amdgcn_rcpf(Z);
    float rZs = __builtin_fmaf(__builtin_fmaf(-Z, r0, 1.0f), r0, r0);
    const f32x2 rZ = f32x2{rZs, rZs};
#pragma unroll
    for (int i = 0; i < 8; ++i) {
      kh[i] = __builtin_elementwise_fma(w[i], rZ, kh[i]);
      f32x2 om = __builtin_elementwise_fma(-w[i], rZ, onev);
      om = __builtin_elementwise_max(om, epsv);
      w[i] = w[i] * om;
    }
  }
}

// Proven sequential-argmax top-32 (round-4 code): jax tie semantics.
// Mutates kh. Cold fallback only.
__device__ __attribute__((noinline)) unsigned top32_seq(f32x2 kh[8], int lane) {
  unsigned mask = 0;
  for (int k = 0; k < KSEL; ++k) {
    float va[8];
    int sa[8];
#pragma unroll
    for (int i = 0; i < 8; ++i) {
      bool tk = kh[i].y > kh[i].x;
      va[i] = tk ? kh[i].y : kh[i].x;
      sa[i] = tk ? 2 * i + 1 : 2 * i;
    }
#pragma unroll
    for (int i = 0; i < 4; ++i) {
      bool tk = va[2 * i + 1] > va[2 * i];
      va[i] = tk ? va[2 * i + 1] : va[2 * i];
      sa[i] = tk ? sa[2 * i + 1] : sa[2 * i];
    }
    bool tk0 = va[1] > va[0];
    bool tk1 = va[3] > va[2];
    float vx = tk0 ? va[1] : va[0], vy = tk1 ? va[3] : va[2];
    int sx = tk0 ? sa[1] : sa[0], sy = tk1 ? sa[3] : sa[2];
    bool tk2 = vy > vx;
    float bv = tk2 ? vy : vx;
    int bi = (lane << 4) | (tk2 ? sy : sx);
    amax_step<0x111>(bv, bi);
    amax_step<0x112>(bv, bi);
    amax_step<0x114>(bv, bi);
    amax_step<0x118>(bv, bi);
    amax_step<0x142>(bv, bi);
    amax_step<0x143>(bv, bi);
    const int wbi = __builtin_amdgcn_readlane(bi, 63);
    const int slot = wbi & 15;  // uniform
    const bool mine = (lane == (wbi >> 4));
    if (mine) mask |= 1u << slot;
    const int hs = slot >> 1;
    const bool hi = slot & 1;
#pragma unroll
    for (int i = 0; i < 8; ++i) {
      if (i == hs) {
        if (hi)
          kh[i].y = mine ? -1.0f : kh[i].y;
        else
          kh[i].x = mine ? -1.0f : kh[i].x;
      }
    }
  }
  return mask;
}

// Top-32 SET of khot via threshold binary-search on the uint bit pattern
// (khot >= 0 -> order-isomorphic). Counting via ballot+popcll. Early exit
// when count == 32 (then {>=cand} IS the top-32). Tie path: >T all, ==T in
// ascending global index (jax stable semantics). Verified by popcount;
// falls back to top32_seq if anything is off.
__device__ unsigned top32_mask(f32x2 kh[8], int lane) {
  unsigned lo = 0;
  bool exact = false;
  for (int b = 30; b >= 0; --b) {
    const unsigned cand = lo | (1u << b);
    int c = 0;
#pragma unroll
    for (int i = 0; i < 8; ++i) {
      c += __popcll(__ballot(__float_as_uint(kh[i].x) >= cand));
      c += __popcll(__ballot(__float_as_uint(kh[i].y) >= cand));
    }
    if (c >= 32) {
      lo = cand;
      if (c == 32) { exact = true; break; }
    }
  }

  unsigned mask;
  if (exact) {
    mask = 0;
#pragma unroll
    for (int i = 0; i < 8; ++i) {
      mask |= (__float_as_uint(kh[i].x) >= lo ? 1u : 0u) << (2 * i);
      mask |= (__float_as_uint(kh[i].y) >= lo ? 1u : 0u) << (2 * i + 1);
    }
  } else {
    const unsigned T = lo;
    unsigned gt = 0, eq = 0;
#pragma unroll
    for (int i = 0; i < 8; ++i) {
      const unsigned ux = __float_as_uint(kh[i].x);
      const unsigned uy = __float_as_uint(kh[i].y);
      gt |= (ux > T ? 1u : 0u) << (2 * i);
      gt |= (uy > T ? 1u : 0u) << (2 * i + 1);
      eq |= (ux == T ? 1u : 0u) << (2 * i);
      eq |= (uy == T ? 1u : 0u) << (2 * i + 1);
    }
    const int n_gt = wave_isum64(__popc(gt));
    const int m = 32 - n_gt;  // uniform
    const int pe = __popc(eq);
    const int be = wave_iscan64(pe) - pe;  // exclusive prefix of tie counts
    int need = m - be;
    need = need < 0 ? 0 : (need > pe ? pe : need);
    unsigned tk = 0;
    unsigned em = eq;
    for (int guard = 0; guard < 16; ++guard) {
      if (!__any(need > 0)) break;
      if (need > 0) {
        const int bpos = __ffs(em) - 1;
        tk |= 1u << bpos;
        em &= em - 1;
        --need;
      }
    }
    mask = gt | tk;
  }

  // safety net: exact-32 check with the proven float reduction
  const float tot = wave_sum64_dpp((float)__popc(mask));
  if (tot != 32.0f) mask = top32_seq(kh, lane);  // cold, uniform branch
  return mask;
}

// ---- precompute, stage 1 (grid 256): the two length-1024 dot layers ----
extern "C" __global__ void pcfs_pre1(const float* __restrict__ ba,
                                     const float* __restrict__ W1a,
                                     const float* __restrict__ b1a,
                                     const float* __restrict__ bb,
                                     const float* __restrict__ W1b,
                                     float* __restrict__ ws) {
  const int b = blockIdx.x;
  const int t = threadIdx.x;
  float acc = 0.0f;
  if (b < 128) {
#pragma unroll
    for (int j = t; j < N_ORB; j += 256) acc += ba[j] * W1a[j * 128 + b];
  } else {
    const int n = b - 128;
#pragma unroll
    for (int j = t; j < N_ORB; j += 256) acc += bb[j] * W1b[j * 128 + n];
  }
  __shared__ float red[4];
  float wsum = wave_sum64_dpp(acc);
  if ((t & 63) == 0) red[t >> 6] = wsum;
  __syncthreads();
  if (t == 0) {
    float tot = red[0] + red[1] + red[2] + red[3];
    if (b < 128)
      ws[1152 + b] = leaky(tot + b1a[b]);
    else
      ws[N_ORB + (b - 128)] = tot;
  }
}

// ---- precompute, stage 2 (1 block x 1024): h2 + alpha const logits ----
extern "C" __global__ void pcfs_pre2(const float* __restrict__ ba,
                                     const float* __restrict__ W2a,
                                     const float* __restrict__ b2a,
                                     const float* __restrict__ W3a,
                                     const float* __restrict__ b3a,
                                     float* __restrict__ ws) {
  __shared__ float h1[128];
  __shared__ float h2[64];
  const int t = threadIdx.x;
  if (t < 128) h1[t] = ws[1152 + t];
  __syncthreads();
  if (t < 64) {
    float acc = b2a[t];
#pragma unroll 8
    for (int n = 0; n < 128; ++n) acc += h1[n] * W2a[n * 64 + t];
    h2[t] = leaky(acc);
  }
  __syncthreads();
  float acc = b3a[t];
#pragma unroll 8
  for (int m = 0; m < 64; ++m) acc += h2[m] * W3a[m * N_ORB + t];
  ws[t] = acc + ba[t];  // + base_a
}

// One wave per batch row. 256 threads = 4 independent waves, no barriers.
extern "C" __global__ void __launch_bounds__(256, 4) pcfs_sampler(
    const float* __restrict__ ws, const float* __restrict__ Wc,
    const float* __restrict__ bc, const float* __restrict__ W1b,
    const float* __restrict__ b1b, const float* __restrict__ W2b,
    const float* __restrict__ b2b, const float* __restrict__ W3b,
    const float* __restrict__ b3b, const float* __restrict__ bb,
    const float* __restrict__ g_alpha, const float* __restrict__ g_beta,
    float* __restrict__ out, int B) {
  const int wave = threadIdx.x >> 6;
  const int lane = threadIdx.x & 63;
  const int row = blockIdx.x * 4 + wave;
  if (row >= B) return;

  // ---- alpha chain: w = exp2((const_logits + gumbel) * log2e) ----
  f32x2 w[8], kh[8];
  {
    const float4* c4 = (const float4*)ws;
    const float4* g4 = (const float4*)(g_alpha + (size_t)row * N_ORB);
#pragma unroll
    for (int q = 0; q < 4; ++q) {
      float4 c = c4[lane * 4 + q];
      float4 g = g4[lane * 4 + q];
      w[2 * q + 0].x = __builtin_amdgcn_exp2f((c.x + g.x) * LOG2E);
      w[2 * q + 0].y = __builtin_amdgcn_exp2f((c.y + g.y) * LOG2E);
      w[2 * q + 1].x = __builtin_amdgcn_exp2f((c.z + g.z) * LOG2E);
      w[2 * q + 1].y = __builtin_amdgcn_exp2f((c.w + g.w) * LOG2E);
    }
  }
  run_chain(w, kh);
  const unsigned amask = top32_mask(kh, lane);

  // write alpha half (hard config: exact 0/1)
  {
    float4* o4 = (float4*)(out + (size_t)row * (2 * N_ORB));
#pragma unroll
    for (int q = 0; q < 4; ++q) {
      float4 o;
      o.x = ((amask >> (4 * q + 0)) & 1) ? 1.0f : 0.0f;
      o.y = ((amask >> (4 * q + 1)) & 1) ? 1.0f : 0.0f;
      o.z = ((amask >> (4 * q + 2)) & 1) ? 1.0f : 0.0f;
      o.w = ((amask >> (4 * q + 3)) & 1) ? 1.0f : 0.0f;
      o4[lane * 4 + q] = o;
    }
  }

  // ---- ctx = alpha_config @ Wc + bc: scalar-driven gather, ascending idx ----
  float ctxv = bc[lane & 31];
  {
    unsigned long long act = __ballot(amask != 0);
    int got = 0;
    while (got < 32 && act) {
      const int l = __ffsll((unsigned long long)act) - 1;  // uniform
      unsigned m16 = (unsigned)__builtin_amdgcn_readlane((int)amask, l);
      act &= act - 1;
      while (m16) {  // uniform scalar loop
        const int s = __ffs(m16) - 1;
        m16 &= m16 - 1;
        const int idx = (l << 4) | s;
        ctxv += Wc[idx * 32 + (lane & 31)];
        ++got;
      }
    }
  }

  // ---- h1 = leaky(base_b@W1b[0:1024] + ctx@W1b[1024:1056] + b1b) ----
  float h1a = b1b[lane] + ws[N_ORB + lane];
  float h1b = b1b[lane + 64] + ws[N_ORB + lane + 64];
#pragma unroll 4
  for (int c = 0; c < 32; ++c) {
    const float cv = rdlane(ctxv, c);
    const float* wr = W1b + (size_t)(N_ORB + c) * 128;
    h1a += cv * wr[lane];
    h1b += cv * wr[lane + 64];
  }
  h1a = leaky(h1a);
  h1b = leaky(h1b);

  // ---- h2 = leaky(h1 @ W2b + b2b) ----
  float h2v = b2b[lane];
#pragma unroll 4
  for (int n = 0; n < 64; ++n) {
    const float hv = rdlane(h1a, n);
    h2v += hv * W2b[n * 64 + lane];
  }
#pragma unroll 4
  for (int n = 0; n < 64; ++n) {
    const float hv = rdlane(h1b, n);
    h2v += hv * W2b[(n + 64) * 64 + lane];
  }
  h2v = leaky(h2v);

  // ---- beta logits = h2 @ W3b + b3b (+ base_b), + gumbel -> w (packed) ----
  f32x2 acc2[8];
  {
    const float4* b4 = (const float4*)b3b;
#pragma unroll
    for (int q = 0; q < 4; ++q) {
      float4 b = b4[lane * 4 + q];
      acc2[2 * q + 0] = f32x2{b.x, b.y};
      acc2[2 * q + 1] = f32x2{b.z, b.w};
    }
  }
  for (int m = 0; m < 64; ++m) {
    const float hm = rdlane(h2v, m);
    const f32x2 hm2 = f32x2{hm, hm};
    const float4* w4 = (const float4*)(W3b + m * N_ORB);
#pragma unroll
    for (int q = 0; q < 4; ++q) {
      float4 wv = w4[lane * 4 + q];
      acc2[2 * q + 0] =
          __builtin_elementwise_fma(f32x2{wv.x, wv.y}, hm2, acc2[2 * q + 0]);
      acc2[2 * q + 1] =
          __builtin_elementwise_fma(f32x2{wv.z, wv.w}, hm2, acc2[2 * q + 1]);
    }
  }
  {
    const float4* bb4 = (const float4*)bb;
    const float4* g4 = (const float4*)(g_beta + (size_t)row * N_ORB);
#pragma unroll
    for (int q = 0; q < 4; ++q) {
      float4 b = bb4[lane * 4 + q];
      float4 g = g4[lane * 4 + q];
      w[2 * q + 0].x = __builtin_amdgcn_exp2f((acc2[2 * q + 0].x + b.x + g.x) * LOG2E);
      w[2 * q + 0].y = __builtin_amdgcn_exp2f((acc2[2 * q + 0].y + b.y + g.y) * LOG2E);
      w[2 * q + 1].x = __builtin_amdgcn_exp2f((acc2[2 * q + 1].x + b.z + g.z) * LOG2E);
      w[2 * q + 1].y = __builtin_amdgcn_exp2f((acc2[2 * q + 1].y + b.w + g.w) * LOG2E);
    }
  }
  run_chain(w, kh);
  const unsigned bmask = top32_mask(kh, lane);

  {
    float4* o4 = (float4*)(out + (size_t)row * (2 * N_ORB) + N_ORB);
#pragma unroll
    for (int q = 0; q < 4; ++q) {
      float4 o;
      o.x = ((bmask >> (4 * q + 0)) & 1) ? 1.0f : 0.0f;
      o.y = ((bmask >> (4 * q + 1)) & 1) ? 1.0f : 0.0f;
      o.z = ((bmask >> (4 * q + 2)) & 1) ? 1.0f : 0.0f;
      o.w = ((bmask >> (4 * q + 3)) & 1) ? 1.0f : 0.0f;
      o4[lane * 4 + q] = o;
    }
  }
}

extern "C" void kernel_launch(void* const* d_in, const int* in_sizes, int n_in,
                              void* d_out, int out_size, void* d_ws, size_t ws_size,
                              hipStream_t stream) {
  const float* ba  = (const float*)d_in[0];
  const float* W1a = (const float*)d_in[1];
  const float* b1a = (const float*)d_in[2];
  const float* W2a = (const float*)d_in[3];
  const float* b2a = (const float*)d_in[4];
  const float* W3a = (const float*)d_in[5];
  const float* b3a = (const float*)d_in[6];
  const float* bb  = (const float*)d_in[7];
  const float* Wc  = (const float*)d_in[8];
  const float* bc  = (const float*)d_in[9];
  const float* W1b = (const float*)d_in[10];
  const float* b1b = (const float*)d_in[11];
  const float* W2b = (const float*)d_in[12];
  const float* b2b = (const float*)d_in[13];
  const float* W3b = (const float*)d_in[14];
  const float* b3b = (const float*)d_in[15];
  const float* ga  = (const float*)d_in[16];
  const float* gbt = (const float*)d_in[17];
  const int B = in_sizes[16] / N_ORB;
  float* ws = (float*)d_ws;

  hipLaunchKernelGGL(pcfs_pre1, dim3(256), dim3(256), 0, stream,
                     ba, W1a, b1a, bb, W1b, ws);
  hipLaunchKernelGGL(pcfs_pre2, dim3(1), dim3(1024), 0, stream,
                     ba, W2a, b2a, W3a, b3a, ws);
  hipLaunchKernelGGL(pcfs_sampler, dim3((B + 3) / 4), dim3(256), 0, stream,
                     ws, Wc, bc, W1b, b1b, W2b, b2b, W3b, b3b, bb,
                     ga, gbt, (float*)d_out, B);
}

// Round 7
// 356.826 us; speedup vs baseline: 1.9045x; 1.0246x over previous
//
#include <hip/hip_runtime.h>
#include <hip/hip_bf16.h>
#include <float.h>

#define N_ORB 1024
#define KSEL 32
#define LEAK 0.01f
#define EPSV 1e-20f
#define LOG2E 1.4426950408889634f

typedef float f32x2 __attribute__((ext_vector_type(2)));
// NOTE: never write (f32x2)(a, b) — in C++ that's a comma-expr cast that
// SPLATS b. Use f32x2{a, b}.

__device__ __forceinline__ float leaky(float x) { return x >= 0.0f ? x : LEAK * x; }

// ---- DPP helpers ----
template <int CTRL, int RM>
__device__ __forceinline__ int dpp0_i(int v) {  // masked-off rows contribute 0
  return __builtin_amdgcn_update_dpp(0, v, CTRL, RM, 0xF, true);
}
template <int CTRL>
__device__ __forceinline__ float dpp_zero(float v) {
  return __int_as_float(
      __builtin_amdgcn_update_dpp(0, __float_as_int(v), CTRL, 0xF, 0xF, true));
}
__device__ __forceinline__ float rdlane(float v, int l) {
  return __int_as_float(__builtin_amdgcn_readlane(__float_as_int(v), l));
}

// full 64-lane float sum, uniform result
__device__ __forceinline__ float wave_sum64_dpp(float v) {
  v += dpp_zero<0x111>(v);
  v += dpp_zero<0x112>(v);
  v += dpp_zero<0x114>(v);
  v += dpp_zero<0x118>(v);
  v += dpp_zero<0x142>(v);
  v += dpp_zero<0x143>(v);
  return rdlane(v, 63);
}
// full 64-lane int sum, uniform result
__device__ __forceinline__ int wave_isum64(int v) {
  v += dpp0_i<0x111, 0xF>(v);
  v += dpp0_i<0x112, 0xF>(v);
  v += dpp0_i<0x114, 0xF>(v);
  v += dpp0_i<0x118, 0xF>(v);
  v += dpp0_i<0x142, 0xF>(v);
  v += dpp0_i<0x143, 0xF>(v);
  return __builtin_amdgcn_readlane(v, 63);
}
// 64-lane inclusive prefix sum (int), per-lane result
__device__ __forceinline__ int wave_iscan64(int v) {
  v += dpp0_i<0x111, 0xF>(v);
  v += dpp0_i<0x112, 0xF>(v);
  v += dpp0_i<0x114, 0xF>(v);
  v += dpp0_i<0x118, 0xF>(v);
  v += dpp0_i<0x142, 0xA>(v);  // bcast15 into rows 1,3
  v += dpp0_i<0x143, 0xC>(v);  // bcast31 into rows 2,3
  return v;
}

// Successive-softmax chain, multiplicative form (w tracks exp(s)); khot out.
__device__ void run_chain(f32x2 w[8], f32x2 kh[8]) {
#pragma unroll
  for (int i = 0; i < 8; ++i) kh[i] = f32x2{0.0f, 0.0f};
  const f32x2 onev = f32x2{1.0f, 1.0f};
  const f32x2 epsv = f32x2{EPSV, EPSV};
  for (int it = 0; it < KSEL; ++it) {
    f32x2 s01 = w[0] + w[1], s23 = w[2] + w[3];
    f32x2 s45 = w[4] + w[5], s67 = w[6] + w[7];
    s01 += s23;
    s45 += s67;
    s01 += s45;
    float Z = wave_sum64_dpp(s01.x + s01.y);
    Z = fmaxf(Z, 1e-30f);
    float r0 = __builtin_amdgcn_rcpf(Z);
    float rZs = __builtin_fmaf(__builtin_fmaf(-Z, r0, 1.0f), r0, r0);
    const f32x2 rZ = f32x2{rZs, rZs};
#pragma unroll
    for (int i = 0; i < 8; ++i) {
      kh[i] = __builtin_elementwise_fma(w[i], rZ, kh[i]);
      f32x2 om = __builtin_elementwise_fma(-w[i], rZ, onev);
      om = __builtin_elementwise_max(om, epsv);
      w[i] = w[i] * om;
    }
  }
}

// Top-32 SET of khot via threshold binary-search on the uint bit pattern
// (khot >= 0 -> order-isomorphic). Counting via ballot+popcll (SALU
// co-issue). Early exit when count == 32 (then {>=cand} IS the top-32).
// Tie path: all >T, then ==T in ascending global index (jax stable tie
// semantics; global index = (lane<<4)|slot).
//
// Correctness invariant (no fallback needed): the search keeps
// count(>=lo) >= 32 (lo=0 counts 1024) and ends with lo maximal, so
// count(>lo) < 32 and count(==lo) >= 32-count(>lo); the tie path always
// completes exactly 32. khot cannot be NaN (w >= 0 finite, Z clamped).
// Field-validated in round 6 with a live popcount verifier (absmax 0).
__device__ unsigned top32_mask(const f32x2 kh[8], int lane) {
  unsigned lo = 0;
  bool exact = false;
  for (int b = 30; b >= 0; --b) {
    const unsigned cand = lo | (1u << b);
    int c = 0;
#pragma unroll
    for (int i = 0; i < 8; ++i) {
      c += __popcll(__ballot(__float_as_uint(kh[i].x) >= cand));
      c += __popcll(__ballot(__float_as_uint(kh[i].y) >= cand));
    }
    if (c >= 32) {
      lo = cand;
      if (c == 32) { exact = true; break; }
    }
  }

  if (exact) {
    unsigned mask = 0;
#pragma unroll
    for (int i = 0; i < 8; ++i) {
      mask |= (__float_as_uint(kh[i].x) >= lo ? 1u : 0u) << (2 * i);
      mask |= (__float_as_uint(kh[i].y) >= lo ? 1u : 0u) << (2 * i + 1);
    }
    return mask;
  }

  const unsigned T = lo;
  unsigned gt = 0, eq = 0;
#pragma unroll
  for (int i = 0; i < 8; ++i) {
    const unsigned ux = __float_as_uint(kh[i].x);
    const unsigned uy = __float_as_uint(kh[i].y);
    gt |= (ux > T ? 1u : 0u) << (2 * i);
    gt |= (uy > T ? 1u : 0u) << (2 * i + 1);
    eq |= (ux == T ? 1u : 0u) << (2 * i);
    eq |= (uy == T ? 1u : 0u) << (2 * i + 1);
  }
  const int n_gt = wave_isum64(__popc(gt));
  const int m = 32 - n_gt;  // uniform, >= 1
  const int pe = __popc(eq);
  const int be = wave_iscan64(pe) - pe;  // exclusive prefix of tie counts
  int need = m - be;
  need = need < 0 ? 0 : (need > pe ? pe : need);
  unsigned tk = 0;
  unsigned em = eq;
  for (int guard = 0; guard < 16; ++guard) {
    if (!__any(need > 0)) break;
    if (need > 0) {
      const int bpos = __ffs(em) - 1;
      tk |= 1u << bpos;
      em &= em - 1;
      --need;
    }
  }
  return gt | tk;
}

// ---- precompute, stage 1 (grid 256): the two length-1024 dot layers ----
extern "C" __global__ void pcfs_pre1(const float* __restrict__ ba,
                                     const float* __restrict__ W1a,
                                     const float* __restrict__ b1a,
                                     const float* __restrict__ bb,
                                     const float* __restrict__ W1b,
                                     float* __restrict__ ws) {
  const int b = blockIdx.x;
  const int t = threadIdx.x;
  float acc = 0.0f;
  if (b < 128) {
#pragma unroll
    for (int j = t; j < N_ORB; j += 256) acc += ba[j] * W1a[j * 128 + b];
  } else {
    const int n = b - 128;
#pragma unroll
    for (int j = t; j < N_ORB; j += 256) acc += bb[j] * W1b[j * 128 + n];
  }
  __shared__ float red[4];
  float wsum = wave_sum64_dpp(acc);
  if ((t & 63) == 0) red[t >> 6] = wsum;
  __syncthreads();
  if (t == 0) {
    float tot = red[0] + red[1] + red[2] + red[3];
    if (b < 128)
      ws[1152 + b] = leaky(tot + b1a[b]);
    else
      ws[N_ORB + (b - 128)] = tot;
  }
}

// ---- precompute, stage 2 (1 block x 1024): h2 + alpha const logits ----
extern "C" __global__ void pcfs_pre2(const float* __restrict__ ba,
                                     const float* __restrict__ W2a,
                                     const float* __restrict__ b2a,
                                     const float* __restrict__ W3a,
                                     const float* __restrict__ b3a,
                                     float* __restrict__ ws) {
  __shared__ float h1[128];
  __shared__ float h2[64];
  const int t = threadIdx.x;
  if (t < 128) h1[t] = ws[1152 + t];
  __syncthreads();
  if (t < 64) {
    float acc = b2a[t];
#pragma unroll 8
    for (int n = 0; n < 128; ++n) acc += h1[n] * W2a[n * 64 + t];
    h2[t] = leaky(acc);
  }
  __syncthreads();
  float acc = b3a[t];
#pragma unroll 8
  for (int m = 0; m < 64; ++m) acc += h2[m] * W3a[m * N_ORB + t];
  ws[t] = acc + ba[t];  // + base_a
}

// One wave per batch row. 256 threads = 4 independent waves, no barriers.
extern "C" __global__ void __launch_bounds__(256, 4) pcfs_sampler(
    const float* __restrict__ ws, const float* __restrict__ Wc,
    const float* __restrict__ bc, const float* __restrict__ W1b,
    const float* __restrict__ b1b, const float* __restrict__ W2b,
    const float* __restrict__ b2b, const float* __restrict__ W3b,
    const float* __restrict__ b3b, const float* __restrict__ bb,
    const float* __restrict__ g_alpha, const float* __restrict__ g_beta,
    float* __restrict__ out, int B) {
  const int wave = threadIdx.x >> 6;
  const int lane = threadIdx.x & 63;
  const int row = blockIdx.x * 4 + wave;
  if (row >= B) return;

  // ---- alpha chain: w = exp2((const_logits + gumbel) * log2e) ----
  f32x2 w[8], kh[8];
  {
    const float4* c4 = (const float4*)ws;
    const float4* g4 = (const float4*)(g_alpha + (size_t)row * N_ORB);
#pragma unroll
    for (int q = 0; q < 4; ++q) {
      float4 c = c4[lane * 4 + q];
      float4 g = g4[lane * 4 + q];
      w[2 * q + 0].x = __builtin_amdgcn_exp2f((c.x + g.x) * LOG2E);
      w[2 * q + 0].y = __builtin_amdgcn_exp2f((c.y + g.y) * LOG2E);
      w[2 * q + 1].x = __builtin_amdgcn_exp2f((c.z + g.z) * LOG2E);
      w[2 * q + 1].y = __builtin_amdgcn_exp2f((c.w + g.w) * LOG2E);
    }
  }
  run_chain(w, kh);
  const unsigned amask = top32_mask(kh, lane);

  // write alpha half (hard config: exact 0/1)
  {
    float4* o4 = (float4*)(out + (size_t)row * (2 * N_ORB));
#pragma unroll
    for (int q = 0; q < 4; ++q) {
      float4 o;
      o.x = ((amask >> (4 * q + 0)) & 1) ? 1.0f : 0.0f;
      o.y = ((amask >> (4 * q + 1)) & 1) ? 1.0f : 0.0f;
      o.z = ((amask >> (4 * q + 2)) & 1) ? 1.0f : 0.0f;
      o.w = ((amask >> (4 * q + 3)) & 1) ? 1.0f : 0.0f;
      o4[lane * 4 + q] = o;
    }
  }

  // ---- ctx = alpha_config @ Wc + bc: scalar-driven gather, ascending idx ----
  float ctxv = bc[lane & 31];
  {
    unsigned long long act = __ballot(amask != 0);
    int got = 0;
    while (got < 32 && act) {
      const int l = __ffsll((unsigned long long)act) - 1;  // uniform
      unsigned m16 = (unsigned)__builtin_amdgcn_readlane((int)amask, l);
      act &= act - 1;
      while (m16) {  // uniform scalar loop
        const int s = __ffs(m16) - 1;
        m16 &= m16 - 1;
        const int idx = (l << 4) | s;
        ctxv += Wc[idx * 32 + (lane & 31)];
        ++got;
      }
    }
  }

  // ---- h1 = leaky(base_b@W1b[0:1024] + ctx@W1b[1024:1056] + b1b) ----
  float h1a = b1b[lane] + ws[N_ORB + lane];
  float h1b = b1b[lane + 64] + ws[N_ORB + lane + 64];
#pragma unroll 4
  for (int c = 0; c < 32; ++c) {
    const float cv = rdlane(ctxv, c);
    const float* wr = W1b + (size_t)(N_ORB + c) * 128;
    h1a += cv * wr[lane];
    h1b += cv * wr[lane + 64];
  }
  h1a = leaky(h1a);
  h1b = leaky(h1b);

  // ---- h2 = leaky(h1 @ W2b + b2b) ----
  float h2v = b2b[lane];
#pragma unroll 4
  for (int n = 0; n < 64; ++n) {
    const float hv = rdlane(h1a, n);
    h2v += hv * W2b[n * 64 + lane];
  }
#pragma unroll 4
  for (int n = 0; n < 64; ++n) {
    const float hv = rdlane(h1b, n);
    h2v += hv * W2b[(n + 64) * 64 + lane];
  }
  h2v = leaky(h2v);

  // ---- beta logits = h2 @ W3b + b3b (+ base_b), + gumbel -> w (packed) ----
  f32x2 acc2[8];
  {
    const float4* b4 = (const float4*)b3b;
#pragma unroll
    for (int q = 0; q < 4; ++q) {
      float4 b = b4[lane * 4 + q];
      acc2[2 * q + 0] = f32x2{b.x, b.y};
      acc2[2 * q + 1] = f32x2{b.z, b.w};
    }
  }
  for (int m = 0; m < 64; ++m) {
    const float hm = rdlane(h2v, m);
    const f32x2 hm2 = f32x2{hm, hm};
    const float4* w4 = (const float4*)(W3b + m * N_ORB);
#pragma unroll
    for (int q = 0; q < 4; ++q) {
      float4 wv = w4[lane * 4 + q];
      acc2[2 * q + 0] =
          __builtin_elementwise_fma(f32x2{wv.x, wv.y}, hm2, acc2[2 * q + 0]);
      acc2[2 * q + 1] =
          __builtin_elementwise_fma(f32x2{wv.z, wv.w}, hm2, acc2[2 * q + 1]);
    }
  }
  {
    const float4* bb4 = (const float4*)bb;
    const float4* g4 = (const float4*)(g_beta + (size_t)row * N_ORB);
#pragma unroll
    for (int q = 0; q < 4; ++q) {
      float4 b = bb4[lane * 4 + q];
      float4 g = g4[lane * 4 + q];
      w[2 * q + 0].x = __builtin_amdgcn_exp2f((acc2[2 * q + 0].x + b.x + g.x) * LOG2E);
      w[2 * q + 0].y = __builtin_amdgcn_exp2f((acc2[2 * q + 0].y + b.y + g.y) * LOG2E);
      w[2 * q + 1].x = __builtin_amdgcn_exp2f((acc2[2 * q + 1].x + b.z + g.z) * LOG2E);
      w[2 * q + 1].y = __builtin_amdgcn_exp2f((acc2[2 * q + 1].y + b.w + g.w) * LOG2E);
    }
  }
  run_chain(w, kh);
  const unsigned bmask = top32_mask(kh, lane);

  {
    float4* o4 = (float4*)(out + (size_t)row * (2 * N_ORB) + N_ORB);
#pragma unroll
    for (int q = 0; q < 4; ++q) {
      float4 o;
      o.x = ((bmask >> (4 * q + 0)) & 1) ? 1.0f : 0.0f;
      o.y = ((bmask >> (4 * q + 1)) & 1) ? 1.0f : 0.0f;
      o.z = ((bmask >> (4 * q + 2)) & 1) ? 1.0f : 0.0f;
      o.w = ((bmask >> (4 * q + 3)) & 1) ? 1.0f : 0.0f;
      o4[lane * 4 + q] = o;
    }
  }
}

extern "C" void kernel_launch(void* const* d_in, const int* in_sizes, int n_in,
                              void* d_out, int out_size, void* d_ws, size_t ws_size,
                              hipStream_t stream) {
  const float* ba  = (const float*)d_in[0];
  const float* W1a = (const float*)d_in[1];
  const float* b1a = (const float*)d_in[2];
  const float* W2a = (const float*)d_in[3];
  const float* b2a = (const float*)d_in[4];
  const float* W3a = (const float*)d_in[5];
  const float* b3a = (const float*)d_in[6];
  const float* bb  = (const float*)d_in[7];
  const float* Wc  = (const float*)d_in[8];
  const float* bc  = (const float*)d_in[9];
  const float* W1b = (const float*)d_in[10];
  const float* b1b = (const float*)d_in[11];
  const float* W2b = (const float*)d_in[12];
  const float* b2b = (const float*)d_in[13];
  const float* W3b = (const float*)d_in[14];
  const float* b3b = (const float*)d_in[15];
  const float* ga  = (const float*)d_in[16];
  const float* gbt = (const float*)d_in[17];
  const int B = in_sizes[16] / N_ORB;
  float* ws = (float*)d_ws;

  hipLaunchKernelGGL(pcfs_pre1, dim3(256), dim3(256), 0, stream,
                     ba, W1a, b1a, bb, W1b, ws);
  hipLaunchKernelGGL(pcfs_pre2, dim3(1), dim3(1024), 0, stream,
                     ba, W2a, b2a, W3a, b3a, ws);
  hipLaunchKernelGGL(pcfs_sampler, dim3((B + 3) / 4), dim3(256), 0, stream,
                     ws, Wc, bc, W1b, b1b, W2b, b2b, W3b, b3b, bb,
                     ga, gbt, (float*)d_out, B);
}

// Round 8
// 298.246 us; speedup vs baseline: 2.2786x; 1.1964x over previous
//
#include <hip/hip_runtime.h>
#include <hip/hip_bf16.h>
#include <float.h>

#define N_ORB 1024
#define KSEL 32
#define LEAK 0.01f
#define EPSV 1e-20f
#define LOG2E 1.4426950408889634f

typedef float f32x2 __attribute__((ext_vector_type(2)));
// NOTE: never write (f32x2)(a, b) — in C++ that's a comma-expr cast that
// SPLATS b. Use f32x2{a, b}.

__device__ __forceinline__ float leaky(float x) { return x >= 0.0f ? x : LEAK * x; }

// ---- DPP helpers ----
template <int CTRL, int RM>
__device__ __forceinline__ int dpp0_i(int v) {  // masked-off rows contribute 0
  return __builtin_amdgcn_update_dpp(0, v, CTRL, RM, 0xF, true);
}
template <int CTRL>
__device__ __forceinline__ float dpp_zero(float v) {
  return __int_as_float(
      __builtin_amdgcn_update_dpp(0, __float_as_int(v), CTRL, 0xF, 0xF, true));
}
__device__ __forceinline__ float rdlane(float v, int l) {
  return __int_as_float(__builtin_amdgcn_readlane(__float_as_int(v), l));
}

// full 64-lane float sum, uniform result
__device__ __forceinline__ float wave_sum64_dpp(float v) {
  v += dpp_zero<0x111>(v);
  v += dpp_zero<0x112>(v);
  v += dpp_zero<0x114>(v);
  v += dpp_zero<0x118>(v);
  v += dpp_zero<0x142>(v);
  v += dpp_zero<0x143>(v);
  return rdlane(v, 63);
}
// full 64-lane int sum, uniform result
__device__ __forceinline__ int wave_isum64(int v) {
  v += dpp0_i<0x111, 0xF>(v);
  v += dpp0_i<0x112, 0xF>(v);
  v += dpp0_i<0x114, 0xF>(v);
  v += dpp0_i<0x118, 0xF>(v);
  v += dpp0_i<0x142, 0xF>(v);
  v += dpp0_i<0x143, 0xF>(v);
  return __builtin_amdgcn_readlane(v, 63);
}
// 64-lane inclusive prefix sum (int), per-lane result
__device__ __forceinline__ int wave_iscan64(int v) {
  v += dpp0_i<0x111, 0xF>(v);
  v += dpp0_i<0x112, 0xF>(v);
  v += dpp0_i<0x114, 0xF>(v);
  v += dpp0_i<0x118, 0xF>(v);
  v += dpp0_i<0x142, 0xA>(v);  // bcast15 into rows 1,3
  v += dpp0_i<0x143, 0xC>(v);  // bcast31 into rows 2,3
  return v;
}

// Successive-softmax chain for TWO rows packed in f32x2 (.x=row0,.y=row1),
// multiplicative form (w tracks exp(s)). Element j of a row = lane*16 + j.
// The two rows' Z-reductions are independent -> their DPP chains interleave.
__device__ void run_chain2(f32x2 w[16], f32x2 kh[16]) {
#pragma unroll
  for (int i = 0; i < 16; ++i) kh[i] = f32x2{0.0f, 0.0f};
  const f32x2 onev = f32x2{1.0f, 1.0f};
  const f32x2 epsv = f32x2{EPSV, EPSV};
  for (int it = 0; it < KSEL; ++it) {
    f32x2 t0 = w[0] + w[1], t1 = w[2] + w[3], t2 = w[4] + w[5], t3 = w[6] + w[7];
    f32x2 t4 = w[8] + w[9], t5 = w[10] + w[11], t6 = w[12] + w[13], t7 = w[14] + w[15];
    t0 += t1; t2 += t3; t4 += t5; t6 += t7;
    t0 += t2; t4 += t6;
    t0 += t4;
    float Z0 = wave_sum64_dpp(t0.x);  // independent of Z1 -> interleaved issue
    float Z1 = wave_sum64_dpp(t0.y);
    Z0 = fmaxf(Z0, 1e-30f);
    Z1 = fmaxf(Z1, 1e-30f);
    float r0 = __builtin_amdgcn_rcpf(Z0);
    float r1 = __builtin_amdgcn_rcpf(Z1);
    float rZ0 = __builtin_fmaf(__builtin_fmaf(-Z0, r0, 1.0f), r0, r0);
    float rZ1 = __builtin_fmaf(__builtin_fmaf(-Z1, r1, 1.0f), r1, r1);
    const f32x2 rZ = f32x2{rZ0, rZ1};
#pragma unroll
    for (int i = 0; i < 16; ++i) {
      kh[i] = __builtin_elementwise_fma(w[i], rZ, kh[i]);
      f32x2 om = __builtin_elementwise_fma(-w[i], rZ, onev);
      om = __builtin_elementwise_max(om, epsv);
      w[i] = w[i] * om;
    }
  }
}

// Tie path for one row (cold; comp_y selects component). jax stable tie
// semantics: all >T, then ==T in ascending global index ((lane<<4)|slot).
__device__ unsigned tie_mask16(const f32x2 kh[16], bool comp_y, unsigned T,
                               int lane) {
  unsigned gt = 0, eq = 0;
#pragma unroll
  for (int i = 0; i < 16; ++i) {
    const unsigned u = __float_as_uint(comp_y ? kh[i].y : kh[i].x);
    gt |= (u > T ? 1u : 0u) << i;
    eq |= (u == T ? 1u : 0u) << i;
  }
  const int n_gt = wave_isum64(__popc(gt));
  const int m = 32 - n_gt;  // uniform, >= 1 by search invariant
  const int pe = __popc(eq);
  const int be = wave_iscan64(pe) - pe;  // exclusive prefix of tie counts
  int need = m - be;
  need = need < 0 ? 0 : (need > pe ? pe : need);
  unsigned tk = 0;
  unsigned em = eq;
  for (int guard = 0; guard < 16; ++guard) {
    if (!__any(need > 0)) break;
    if (need > 0) {
      const int bpos = __ffs(em) - 1;
      tk |= 1u << bpos;
      em &= em - 1;
      --need;
    }
  }
  return gt | tk;
}

// Top-32 for both packed rows: joint binary search on the uint views
// (khot >= 0 -> order-isomorphic), ballot+popcll counting, early exit when
// both rows hit count==32 exactly. Invariant (proved r6/r7, field-validated
// with live popcount verifier in r6): tie path always completes exactly 32.
__device__ void top32_mask2(const f32x2 kh[16], int lane, unsigned& m0,
                            unsigned& m1) {
  unsigned lo0 = 0, lo1 = 0;
  bool ex0 = false, ex1 = false;
  for (int b = 30; b >= 0; --b) {
    const unsigned c0v = lo0 | (1u << b);
    const unsigned c1v = lo1 | (1u << b);
    int c0 = 0, c1 = 0;
#pragma unroll
    for (int i = 0; i < 16; ++i) {
      c0 += __popcll(__ballot(__float_as_uint(kh[i].x) >= c0v));
      c1 += __popcll(__ballot(__float_as_uint(kh[i].y) >= c1v));
    }
    if (!ex0 && c0 >= 32) { lo0 = c0v; ex0 = (c0 == 32); }
    if (!ex1 && c1 >= 32) { lo1 = c1v; ex1 = (c1 == 32); }
    if (ex0 && ex1) break;
  }

  if (ex0) {
    unsigned mk = 0;
#pragma unroll
    for (int i = 0; i < 16; ++i)
      mk |= (__float_as_uint(kh[i].x) >= lo0 ? 1u : 0u) << i;
    m0 = mk;
  } else {
    m0 = tie_mask16(kh, false, lo0, lane);
  }
  if (ex1) {
    unsigned mk = 0;
#pragma unroll
    for (int i = 0; i < 16; ++i)
      mk |= (__float_as_uint(kh[i].y) >= lo1 ? 1u : 0u) << i;
    m1 = mk;
  } else {
    m1 = tie_mask16(kh, true, lo1, lane);
  }
}

// ctx accumulate for one row's mask: scalar-driven gather, ascending index
__device__ __forceinline__ float ctx_gather(unsigned mask, int lane,
                                            const float* __restrict__ Wc,
                                            float init) {
  float ctx = init;
  unsigned long long act = __ballot(mask != 0);
  while (act) {
    const int l = __ffsll((unsigned long long)act) - 1;  // uniform
    unsigned m16 = (unsigned)__builtin_amdgcn_readlane((int)mask, l);
    act &= act - 1;
    while (m16) {  // uniform scalar loop
      const int s = __ffs(m16) - 1;
      m16 &= m16 - 1;
      ctx += Wc[((l << 4) | s) * 32 + (lane & 31)];
    }
  }
  return ctx;
}

__device__ __forceinline__ void write_half(float* __restrict__ dst,
                                           unsigned mask, int lane) {
  float4* o4 = (float4*)dst;
#pragma unroll
  for (int q = 0; q < 4; ++q) {
    float4 o;
    o.x = ((mask >> (4 * q + 0)) & 1) ? 1.0f : 0.0f;
    o.y = ((mask >> (4 * q + 1)) & 1) ? 1.0f : 0.0f;
    o.z = ((mask >> (4 * q + 2)) & 1) ? 1.0f : 0.0f;
    o.w = ((mask >> (4 * q + 3)) & 1) ? 1.0f : 0.0f;
    o4[lane * 4 + q] = o;
  }
}

// ---- precompute, stage 1 (grid 256): the two length-1024 dot layers ----
extern "C" __global__ void pcfs_pre1(const float* __restrict__ ba,
                                     const float* __restrict__ W1a,
                                     const float* __restrict__ b1a,
                                     const float* __restrict__ bb,
                                     const float* __restrict__ W1b,
                                     float* __restrict__ ws) {
  const int b = blockIdx.x;
  const int t = threadIdx.x;
  float acc = 0.0f;
  if (b < 128) {
#pragma unroll
    for (int j = t; j < N_ORB; j += 256) acc += ba[j] * W1a[j * 128 + b];
  } else {
    const int n = b - 128;
#pragma unroll
    for (int j = t; j < N_ORB; j += 256) acc += bb[j] * W1b[j * 128 + n];
  }
  __shared__ float red[4];
  float wsum = wave_sum64_dpp(acc);
  if ((t & 63) == 0) red[t >> 6] = wsum;
  __syncthreads();
  if (t == 0) {
    float tot = red[0] + red[1] + red[2] + red[3];
    if (b < 128)
      ws[1152 + b] = leaky(tot + b1a[b]);
    else
      ws[N_ORB + (b - 128)] = tot;
  }
}

// ---- precompute, stage 2 (1 block x 1024): h2 + alpha const logits ----
extern "C" __global__ void pcfs_pre2(const float* __restrict__ ba,
                                     const float* __restrict__ W2a,
                                     const float* __restrict__ b2a,
                                     const float* __restrict__ W3a,
                                     const float* __restrict__ b3a,
                                     float* __restrict__ ws) {
  __shared__ float h1[128];
  __shared__ float h2[64];
  const int t = threadIdx.x;
  if (t < 128) h1[t] = ws[1152 + t];
  __syncthreads();
  if (t < 64) {
    float acc = b2a[t];
#pragma unroll 8
    for (int n = 0; n < 128; ++n) acc += h1[n] * W2a[n * 64 + t];
    h2[t] = leaky(acc);
  }
  __syncthreads();
  float acc = b3a[t];
#pragma unroll 8
  for (int m = 0; m < 64; ++m) acc += h2[m] * W3a[m * N_ORB + t];
  ws[t] = acc + ba[t];  // + base_a
}

// One wave per PAIR of batch rows (.x=row0, .y=row1 in every f32x2).
// 256 threads = 4 independent waves, no barriers.
extern "C" __global__ void __launch_bounds__(256, 4) pcfs_sampler(
    const float* __restrict__ ws, const float* __restrict__ Wc,
    const float* __restrict__ bc, const float* __restrict__ W1b,
    const float* __restrict__ b1b, const float* __restrict__ W2b,
    const float* __restrict__ b2b, const float* __restrict__ W3b,
    const float* __restrict__ b3b, const float* __restrict__ bb,
    const float* __restrict__ g_alpha, const float* __restrict__ g_beta,
    float* __restrict__ out, int B) {
  const int wave = threadIdx.x >> 6;
  const int lane = threadIdx.x & 63;
  const int pair = blockIdx.x * 4 + wave;
  const int row0 = pair * 2;
  if (row0 >= B) return;
  const bool have1 = (row0 + 1 < B);
  const int row1 = have1 ? row0 + 1 : row0;

  f32x2 w[16], kh[16];

  // ---- alpha chains: w = exp2((const_logits + gumbel) * log2e), 2 rows ----
  {
    const float4* c4 = (const float4*)ws;
    const float4* g40 = (const float4*)(g_alpha + (size_t)row0 * N_ORB);
    const float4* g41 = (const float4*)(g_alpha + (size_t)row1 * N_ORB);
#pragma unroll
    for (int q = 0; q < 4; ++q) {
      float4 c = c4[lane * 4 + q];
      float4 g0 = g40[lane * 4 + q];
      float4 g1 = g41[lane * 4 + q];
      w[4 * q + 0] = f32x2{__builtin_amdgcn_exp2f((c.x + g0.x) * LOG2E),
                           __builtin_amdgcn_exp2f((c.x + g1.x) * LOG2E)};
      w[4 * q + 1] = f32x2{__builtin_amdgcn_exp2f((c.y + g0.y) * LOG2E),
                           __builtin_amdgcn_exp2f((c.y + g1.y) * LOG2E)};
      w[4 * q + 2] = f32x2{__builtin_amdgcn_exp2f((c.z + g0.z) * LOG2E),
                           __builtin_amdgcn_exp2f((c.z + g1.z) * LOG2E)};
      w[4 * q + 3] = f32x2{__builtin_amdgcn_exp2f((c.w + g0.w) * LOG2E),
                           __builtin_amdgcn_exp2f((c.w + g1.w) * LOG2E)};
    }
  }
  run_chain2(w, kh);
  unsigned am0, am1;
  top32_mask2(kh, lane, am0, am1);

  // write alpha halves (hard config: exact 0/1)
  write_half(out + (size_t)row0 * (2 * N_ORB), am0, lane);
  if (have1) write_half(out + (size_t)row1 * (2 * N_ORB), am1, lane);

  // ---- ctx = alpha_config @ Wc + bc, per row ----
  const float bcv = bc[lane & 31];
  const float ctx0 = ctx_gather(am0, lane, Wc, bcv);
  const float ctx1 = ctx_gather(am1, lane, Wc, bcv);

  // ---- h1 = leaky(base_b@W1b[0:1024] + ctx@W1b[1024:1056] + b1b) ----
  f32x2 h1a, h1b_;
  {
    const float ia = b1b[lane] + ws[N_ORB + lane];
    const float ib = b1b[lane + 64] + ws[N_ORB + lane + 64];
    h1a = f32x2{ia, ia};
    h1b_ = f32x2{ib, ib};
  }
#pragma unroll 4
  for (int c = 0; c < 32; ++c) {
    const f32x2 cv = f32x2{rdlane(ctx0, c), rdlane(ctx1, c)};
    const float* wr = W1b + (size_t)(N_ORB + c) * 128;
    const float wa = wr[lane], wb = wr[lane + 64];
    h1a = __builtin_elementwise_fma(f32x2{wa, wa}, cv, h1a);
    h1b_ = __builtin_elementwise_fma(f32x2{wb, wb}, cv, h1b_);
  }
  h1a = f32x2{leaky(h1a.x), leaky(h1a.y)};
  h1b_ = f32x2{leaky(h1b_.x), leaky(h1b_.y)};

  // ---- h2 = leaky(h1 @ W2b + b2b) ----
  f32x2 h2v;
  {
    const float i2 = b2b[lane];
    h2v = f32x2{i2, i2};
  }
#pragma unroll 4
  for (int n = 0; n < 64; ++n) {
    const f32x2 hv = f32x2{rdlane(h1a.x, n), rdlane(h1a.y, n)};
    const float wv = W2b[n * 64 + lane];
    h2v = __builtin_elementwise_fma(f32x2{wv, wv}, hv, h2v);
  }
#pragma unroll 4
  for (int n = 0; n < 64; ++n) {
    const f32x2 hv = f32x2{rdlane(h1b_.x, n), rdlane(h1b_.y, n)};
    const float wv = W2b[(n + 64) * 64 + lane];
    h2v = __builtin_elementwise_fma(f32x2{wv, wv}, hv, h2v);
  }
  h2v = f32x2{leaky(h2v.x), leaky(h2v.y)};

  // ---- beta logits: acc (in w[]) = h2 @ W3b + b3b; shared W3b loads ----
  {
    const float4* b4 = (const float4*)b3b;
#pragma unroll
    for (int q = 0; q < 4; ++q) {
      float4 b = b4[lane * 4 + q];
      w[4 * q + 0] = f32x2{b.x, b.x};
      w[4 * q + 1] = f32x2{b.y, b.y};
      w[4 * q + 2] = f32x2{b.z, b.z};
      w[4 * q + 3] = f32x2{b.w, b.w};
    }
  }
  for (int m = 0; m < 64; ++m) {
    const f32x2 hm = f32x2{rdlane(h2v.x, m), rdlane(h2v.y, m)};
    const float4* w4 = (const float4*)(W3b + m * N_ORB);
#pragma unroll
    for (int q = 0; q < 4; ++q) {
      float4 wv = w4[lane * 4 + q];
      w[4 * q + 0] = __builtin_elementwise_fma(f32x2{wv.x, wv.x}, hm, w[4 * q + 0]);
      w[4 * q + 1] = __builtin_elementwise_fma(f32x2{wv.y, wv.y}, hm, w[4 * q + 1]);
      w[4 * q + 2] = __builtin_elementwise_fma(f32x2{wv.z, wv.z}, hm, w[4 * q + 2]);
      w[4 * q + 3] = __builtin_elementwise_fma(f32x2{wv.w, wv.w}, hm, w[4 * q + 3]);
    }
  }
  // + base_b + gumbel -> w = exp2(logits * log2e)
  {
    const float4* bb4 = (const float4*)bb;
    const float4* g40 = (const float4*)(g_beta + (size_t)row0 * N_ORB);
    const float4* g41 = (const float4*)(g_beta + (size_t)row1 * N_ORB);
#pragma unroll
    for (int q = 0; q < 4; ++q) {
      float4 b = bb4[lane * 4 + q];
      float4 g0 = g40[lane * 4 + q];
      float4 g1 = g41[lane * 4 + q];
      w[4 * q + 0] = f32x2{
          __builtin_amdgcn_exp2f((w[4 * q + 0].x + b.x + g0.x) * LOG2E),
          __builtin_amdgcn_exp2f((w[4 * q + 0].y + b.x + g1.x) * LOG2E)};
      w[4 * q + 1] = f32x2{
          __builtin_amdgcn_exp2f((w[4 * q + 1].x + b.y + g0.y) * LOG2E),
          __builtin_amdgcn_exp2f((w[4 * q + 1].y + b.y + g1.y) * LOG2E)};
      w[4 * q + 2] = f32x2{
          __builtin_amdgcn_exp2f((w[4 * q + 2].x + b.z + g0.z) * LOG2E),
          __builtin_amdgcn_exp2f((w[4 * q + 2].y + b.z + g1.z) * LOG2E)};
      w[4 * q + 3] = f32x2{
          __builtin_amdgcn_exp2f((w[4 * q + 3].x + b.w + g0.w) * LOG2E),
          __builtin_amdgcn_exp2f((w[4 * q + 3].y + b.w + g1.w) * LOG2E)};
    }
  }
  run_chain2(w, kh);
  unsigned bm0, bm1;
  top32_mask2(kh, lane, bm0, bm1);

  write_half(out + (size_t)row0 * (2 * N_ORB) + N_ORB, bm0, lane);
  if (have1) write_half(out + (size_t)row1 * (2 * N_ORB) + N_ORB, bm1, lane);
}

extern "C" void kernel_launch(void* const* d_in, const int* in_sizes, int n_in,
                              void* d_out, int out_size, void* d_ws, size_t ws_size,
                              hipStream_t stream) {
  const float* ba  = (const float*)d_in[0];
  const float* W1a = (const float*)d_in[1];
  const float* b1a = (const float*)d_in[2];
  const float* W2a = (const float*)d_in[3];
  const float* b2a = (const float*)d_in[4];
  const float* W3a = (const float*)d_in[5];
  const float* b3a = (const float*)d_in[6];
  const float* bb  = (const float*)d_in[7];
  const float* Wc  = (const float*)d_in[8];
  const float* bc  = (const float*)d_in[9];
  const float* W1b = (const float*)d_in[10];
  const float* b1b = (const float*)d_in[11];
  const float* W2b = (const float*)d_in[12];
  const float* b2b = (const float*)d_in[13];
  const float* W3b = (const float*)d_in[14];
  const float* b3b = (const float*)d_in[15];
  const float* ga  = (const float*)d_in[16];
  const float* gbt = (const float*)d_in[17];
  const int B = in_sizes[16] / N_ORB;
  float* ws = (float*)d_ws;

  hipLaunchKernelGGL(pcfs_pre1, dim3(256), dim3(256), 0, stream,
                     ba, W1a, b1a, bb, W1b, ws);
  hipLaunchKernelGGL(pcfs_pre2, dim3(1), dim3(1024), 0, stream,
                     ba, W2a, b2a, W3a, b3a, ws);
  const int pairs = (B + 1) / 2;
  hipLaunchKernelGGL(pcfs_sampler, dim3((pairs + 3) / 4), dim3(256), 0, stream,
                     ws, Wc, bc, W1b, b1b, W2b, b2b, W3b, b3b, bb,
                     ga, gbt, (float*)d_out, B);
}

// Round 9
// 284.836 us; speedup vs baseline: 2.3859x; 1.0471x over previous
//
#include <hip/hip_runtime.h>
#include <hip/hip_bf16.h>
#include <float.h>

#define N_ORB 1024
#define KSEL 32
#define LEAK 0.01f
#define LOG2E 1.4426950408889634f

typedef float f32x2 __attribute__((ext_vector_type(2)));
// NOTE: never write (f32x2)(a, b) — in C++ that's a comma-expr cast that
// SPLATS b. Use f32x2{a, b}.

__device__ __forceinline__ float leaky(float x) { return x >= 0.0f ? x : LEAK * x; }

// ---- DPP helpers ----
template <int CTRL, int RM>
__device__ __forceinline__ int dpp0_i(int v) {  // masked-off rows contribute 0
  return __builtin_amdgcn_update_dpp(0, v, CTRL, RM, 0xF, true);
}
template <int CTRL>
__device__ __forceinline__ float dpp_zero(float v) {
  return __int_as_float(
      __builtin_amdgcn_update_dpp(0, __float_as_int(v), CTRL, 0xF, 0xF, true));
}
__device__ __forceinline__ float rdlane(float v, int l) {
  return __int_as_float(__builtin_amdgcn_readlane(__float_as_int(v), l));
}

// full 64-lane float sum, uniform result
__device__ __forceinline__ float wave_sum64_dpp(float v) {
  v += dpp_zero<0x111>(v);
  v += dpp_zero<0x112>(v);
  v += dpp_zero<0x114>(v);
  v += dpp_zero<0x118>(v);
  v += dpp_zero<0x142>(v);
  v += dpp_zero<0x143>(v);
  return rdlane(v, 63);
}
// full 64-lane int sum, uniform result
__device__ __forceinline__ int wave_isum64(int v) {
  v += dpp0_i<0x111, 0xF>(v);
  v += dpp0_i<0x112, 0xF>(v);
  v += dpp0_i<0x114, 0xF>(v);
  v += dpp0_i<0x118, 0xF>(v);
  v += dpp0_i<0x142, 0xF>(v);
  v += dpp0_i<0x143, 0xF>(v);
  return __builtin_amdgcn_readlane(v, 63);
}
// 64-lane inclusive prefix sum (int), per-lane result
// (within-row shr scan, then bcast15 into rows 1,3 and bcast31 into rows 2,3)
__device__ __forceinline__ int wave_iscan64(int v) {
  v += dpp0_i<0x111, 0xF>(v);
  v += dpp0_i<0x112, 0xF>(v);
  v += dpp0_i<0x114, 0xF>(v);
  v += dpp0_i<0x118, 0xF>(v);
  v += dpp0_i<0x142, 0xA>(v);
  v += dpp0_i<0x143, 0xC>(v);
  return v;
}

// Successive-softmax chain for TWO rows packed in f32x2 (.x=row0,.y=row1),
// multiplicative form (w tracks exp(s)). Element j of a row = lane*16 + j.
// om clamp: min(max(om,0),1) == reference max(om,1e-20) at fp32 granularity
// (both send w to ~0; khot deltas <= 1e-20, far below any boundary), and the
// pattern folds into the VOP3 clamp modifier (free).
__device__ void run_chain2(f32x2 w[16], f32x2 kh[16]) {
#pragma unroll
  for (int i = 0; i < 16; ++i) kh[i] = f32x2{0.0f, 0.0f};
  const f32x2 onev = f32x2{1.0f, 1.0f};
  const f32x2 zerov = f32x2{0.0f, 0.0f};
  for (int it = 0; it < KSEL; ++it) {
    f32x2 t0 = w[0] + w[1], t1 = w[2] + w[3], t2 = w[4] + w[5], t3 = w[6] + w[7];
    f32x2 t4 = w[8] + w[9], t5 = w[10] + w[11], t6 = w[12] + w[13], t7 = w[14] + w[15];
    t0 += t1; t2 += t3; t4 += t5; t6 += t7;
    t0 += t2; t4 += t6;
    t0 += t4;
    float Z0 = wave_sum64_dpp(t0.x);  // independent of Z1 -> interleaved issue
    float Z1 = wave_sum64_dpp(t0.y);
    Z0 = fmaxf(Z0, 1e-30f);
    Z1 = fmaxf(Z1, 1e-30f);
    float r0 = __builtin_amdgcn_rcpf(Z0);
    float r1 = __builtin_amdgcn_rcpf(Z1);
    float rZ0 = __builtin_fmaf(__builtin_fmaf(-Z0, r0, 1.0f), r0, r0);
    float rZ1 = __builtin_fmaf(__builtin_fmaf(-Z1, r1, 1.0f), r1, r1);
    const f32x2 rZ = f32x2{rZ0, rZ1};
#pragma unroll
    for (int i = 0; i < 16; ++i) {
      kh[i] = __builtin_elementwise_fma(w[i], rZ, kh[i]);
      f32x2 om = __builtin_elementwise_fma(-w[i], rZ, onev);
      om = __builtin_elementwise_min(__builtin_elementwise_max(om, zerov), onev);
      w[i] = w[i] * om;
    }
  }
}

// Tie path for one row (cold; comp_y selects component). jax stable tie
// semantics: all >T, then ==T in ascending global index ((lane<<4)|slot).
__device__ unsigned tie_mask16(const f32x2 kh[16], bool comp_y, unsigned T,
                               int lane) {
  unsigned gt = 0, eq = 0;
#pragma unroll
  for (int i = 0; i < 16; ++i) {
    const unsigned u = __float_as_uint(comp_y ? kh[i].y : kh[i].x);
    gt |= (u > T ? 1u : 0u) << i;
    eq |= (u == T ? 1u : 0u) << i;
  }
  const int n_gt = wave_isum64(__popc(gt));
  const int m = 32 - n_gt;  // uniform, >= 1 by search invariant
  const int pe = __popc(eq);
  const int be = wave_iscan64(pe) - pe;  // exclusive prefix of tie counts
  int need = m - be;
  need = need < 0 ? 0 : (need > pe ? pe : need);
  unsigned tk = 0;
  unsigned em = eq;
  for (int guard = 0; guard < 16; ++guard) {
    if (!__any(need > 0)) break;
    if (need > 0) {
      const int bpos = __ffs(em) - 1;
      tk |= 1u << bpos;
      em &= em - 1;
      --need;
    }
  }
  return gt | tk;
}

// Top-32 for both packed rows: joint binary search on the uint views
// (khot >= 0 -> order-isomorphic), ballot+popcll counting, early exit when
// both rows hit count==32 exactly. Invariant (proved r6/r7, field-validated
// with live popcount verifier in r6): tie path always completes exactly 32.
__device__ void top32_mask2(const f32x2 kh[16], int lane, unsigned& m0,
                            unsigned& m1) {
  unsigned lo0 = 0, lo1 = 0;
  bool ex0 = false, ex1 = false;
  for (int b = 30; b >= 0; --b) {
    const unsigned c0v = lo0 | (1u << b);
    const unsigned c1v = lo1 | (1u << b);
    int c0 = 0, c1 = 0;
#pragma unroll
    for (int i = 0; i < 16; ++i) {
      c0 += __popcll(__ballot(__float_as_uint(kh[i].x) >= c0v));
      c1 += __popcll(__ballot(__float_as_uint(kh[i].y) >= c1v));
    }
    if (!ex0 && c0 >= 32) { lo0 = c0v; ex0 = (c0 == 32); }
    if (!ex1 && c1 >= 32) { lo1 = c1v; ex1 = (c1 == 32); }
    if (ex0 && ex1) break;
  }

  if (ex0) {
    unsigned mk = 0;
#pragma unroll
    for (int i = 0; i < 16; ++i)
      mk |= (__float_as_uint(kh[i].x) >= lo0 ? 1u : 0u) << i;
    m0 = mk;
  } else {
    m0 = tie_mask16(kh, false, lo0, lane);
  }
  if (ex1) {
    unsigned mk = 0;
#pragma unroll
    for (int i = 0; i < 16; ++i)
      mk |= (__float_as_uint(kh[i].y) >= lo1 ? 1u : 0u) << i;
    m1 = mk;
  } else {
    m1 = tie_mask16(kh, true, lo1, lane);
  }
}

// Compact the 32 selected global indices of one row's mask into dst[0..31],
// ascending global index order ((lane<<4)|slot). Intra-wave LDS scatter;
// no barrier needed (same wave).
__device__ __forceinline__ void compact_idx(unsigned mask, int lane,
                                            int* __restrict__ dst) {
  const int pe = __popc(mask);
  int base = wave_iscan64(pe) - pe;  // exclusive prefix across lanes
  unsigned m = mask;
  while (m) {
    const int s = __ffs(m) - 1;
    m &= m - 1;
    dst[base++] = (lane << 4) | s;
  }
}

__device__ __forceinline__ void write_half(float* __restrict__ dst,
                                           unsigned mask, int lane) {
  float4* o4 = (float4*)dst;
#pragma unroll
  for (int q = 0; q < 4; ++q) {
    float4 o;
    o.x = ((mask >> (4 * q + 0)) & 1) ? 1.0f : 0.0f;
    o.y = ((mask >> (4 * q + 1)) & 1) ? 1.0f : 0.0f;
    o.z = ((mask >> (4 * q + 2)) & 1) ? 1.0f : 0.0f;
    o.w = ((mask >> (4 * q + 3)) & 1) ? 1.0f : 0.0f;
    o4[lane * 4 + q] = o;
  }
}

// ---- precompute, stage 1 (grid 256): the two length-1024 dot layers ----
extern "C" __global__ void pcfs_pre1(const float* __restrict__ ba,
                                     const float* __restrict__ W1a,
                                     const float* __restrict__ b1a,
                                     const float* __restrict__ bb,
                                     const float* __restrict__ W1b,
                                     float* __restrict__ ws) {
  const int b = blockIdx.x;
  const int t = threadIdx.x;
  float acc = 0.0f;
  if (b < 128) {
#pragma unroll
    for (int j = t; j < N_ORB; j += 256) acc += ba[j] * W1a[j * 128 + b];
  } else {
    const int n = b - 128;
#pragma unroll
    for (int j = t; j < N_ORB; j += 256) acc += bb[j] * W1b[j * 128 + n];
  }
  __shared__ float red[4];
  float wsum = wave_sum64_dpp(acc);
  if ((t & 63) == 0) red[t >> 6] = wsum;
  __syncthreads();
  if (t == 0) {
    float tot = red[0] + red[1] + red[2] + red[3];
    if (b < 128)
      ws[1152 + b] = leaky(tot + b1a[b]);
    else
      ws[N_ORB + (b - 128)] = tot;
  }
}

// ---- precompute, stage 2 (1 block x 1024): h2 + alpha const logits ----
extern "C" __global__ void pcfs_pre2(const float* __restrict__ ba,
                                     const float* __restrict__ W2a,
                                     const float* __restrict__ b2a,
                                     const float* __restrict__ W3a,
                                     const float* __restrict__ b3a,
                                     float* __restrict__ ws) {
  __shared__ float h1[128];
  __shared__ float h2[64];
  const int t = threadIdx.x;
  if (t < 128) h1[t] = ws[1152 + t];
  __syncthreads();
  if (t < 64) {
    float acc = b2a[t];
#pragma unroll 8
    for (int n = 0; n < 128; ++n) acc += h1[n] * W2a[n * 64 + t];
    h2[t] = leaky(acc);
  }
  __syncthreads();
  float acc = b3a[t];
#pragma unroll 8
  for (int m = 0; m < 64; ++m) acc += h2[m] * W3a[m * N_ORB + t];
  ws[t] = acc + ba[t];  // + base_a
}

// One wave per PAIR of batch rows (.x=row0, .y=row1 in every f32x2).
// 256 threads = 4 independent waves, no barriers.
extern "C" __global__ void __launch_bounds__(256, 4) pcfs_sampler(
    const float* __restrict__ ws, const float* __restrict__ Wc,
    const float* __restrict__ bc, const float* __restrict__ W1b,
    const float* __restrict__ b1b, const float* __restrict__ W2b,
    const float* __restrict__ b2b, const float* __restrict__ W3b,
    const float* __restrict__ b3b, const float* __restrict__ bb,
    const float* __restrict__ g_alpha, const float* __restrict__ g_beta,
    float* __restrict__ out, int B) {
  __shared__ int sidx[4][64];  // per-wave: [0..31]=row0 idxs, [32..63]=row1
  const int wave = threadIdx.x >> 6;
  const int lane = threadIdx.x & 63;
  const int pair = blockIdx.x * 4 + wave;
  const int row0 = pair * 2;
  if (row0 >= B) return;
  const bool have1 = (row0 + 1 < B);
  const int row1 = have1 ? row0 + 1 : row0;

  f32x2 w[16], kh[16];

  // ---- alpha chains: w = exp2((const_logits + gumbel) * log2e), 2 rows ----
  {
    const float4* c4 = (const float4*)ws;
    const float4* g40 = (const float4*)(g_alpha + (size_t)row0 * N_ORB);
    const float4* g41 = (const float4*)(g_alpha + (size_t)row1 * N_ORB);
#pragma unroll
    for (int q = 0; q < 4; ++q) {
      float4 c = c4[lane * 4 + q];
      float4 g0 = g40[lane * 4 + q];
      float4 g1 = g41[lane * 4 + q];
      w[4 * q + 0] = f32x2{__builtin_amdgcn_exp2f((c.x + g0.x) * LOG2E),
                           __builtin_amdgcn_exp2f((c.x + g1.x) * LOG2E)};
      w[4 * q + 1] = f32x2{__builtin_amdgcn_exp2f((c.y + g0.y) * LOG2E),
                           __builtin_amdgcn_exp2f((c.y + g1.y) * LOG2E)};
      w[4 * q + 2] = f32x2{__builtin_amdgcn_exp2f((c.z + g0.z) * LOG2E),
                           __builtin_amdgcn_exp2f((c.z + g1.z) * LOG2E)};
      w[4 * q + 3] = f32x2{__builtin_amdgcn_exp2f((c.w + g0.w) * LOG2E),
                           __builtin_amdgcn_exp2f((c.w + g1.w) * LOG2E)};
    }
  }
  run_chain2(w, kh);
  unsigned am0, am1;
  top32_mask2(kh, lane, am0, am1);

  // write alpha halves (hard config: exact 0/1)
  write_half(out + (size_t)row0 * (2 * N_ORB), am0, lane);
  if (have1) write_half(out + (size_t)row1 * (2 * N_ORB), am1, lane);

  // ---- ctx = alpha_config @ Wc + bc, per row ----
  // Compact selected indices to LDS, then a fixed-trip unrolled loop of
  // uniform-index loads: all 64 Wc loads issue back-to-back (one latency).
  compact_idx(am0, lane, &sidx[wave][0]);
  compact_idx(am1, lane, &sidx[wave][32]);
  const int vi0 = sidx[wave][lane & 31];
  const int vi1 = sidx[wave][32 + (lane & 31)];
  const float bcv = bc[lane & 31];
  float ctx0 = bcv, ctx1 = bcv;
#pragma unroll
  for (int r = 0; r < 32; ++r) {
    const int i0 = __builtin_amdgcn_readlane(vi0, r);  // uniform
    const int i1 = __builtin_amdgcn_readlane(vi1, r);
    ctx0 += Wc[i0 * 32 + (lane & 31)];
    ctx1 += Wc[i1 * 32 + (lane & 31)];
  }

  // ---- h1 = leaky(base_b@W1b[0:1024] + ctx@W1b[1024:1056] + b1b) ----
  f32x2 h1a, h1b_;
  {
    const float ia = b1b[lane] + ws[N_ORB + lane];
    const float ib = b1b[lane + 64] + ws[N_ORB + lane + 64];
    h1a = f32x2{ia, ia};
    h1b_ = f32x2{ib, ib};
  }
#pragma unroll 4
  for (int c = 0; c < 32; ++c) {
    const f32x2 cv = f32x2{rdlane(ctx0, c), rdlane(ctx1, c)};
    const float* wr = W1b + (size_t)(N_ORB + c) * 128;
    const float wa = wr[lane], wb = wr[lane + 64];
    h1a = __builtin_elementwise_fma(f32x2{wa, wa}, cv, h1a);
    h1b_ = __builtin_elementwise_fma(f32x2{wb, wb}, cv, h1b_);
  }
  h1a = f32x2{leaky(h1a.x), leaky(h1a.y)};
  h1b_ = f32x2{leaky(h1b_.x), leaky(h1b_.y)};

  // ---- h2 = leaky(h1 @ W2b + b2b) ----
  f32x2 h2v;
  {
    const float i2 = b2b[lane];
    h2v = f32x2{i2, i2};
  }
#pragma unroll 4
  for (int n = 0; n < 64; ++n) {
    const f32x2 hv = f32x2{rdlane(h1a.x, n), rdlane(h1a.y, n)};
    const float wv = W2b[n * 64 + lane];
    h2v = __builtin_elementwise_fma(f32x2{wv, wv}, hv, h2v);
  }
#pragma unroll 4
  for (int n = 0; n < 64; ++n) {
    const f32x2 hv = f32x2{rdlane(h1b_.x, n), rdlane(h1b_.y, n)};
    const float wv = W2b[(n + 64) * 64 + lane];
    h2v = __builtin_elementwise_fma(f32x2{wv, wv}, hv, h2v);
  }
  h2v = f32x2{leaky(h2v.x), leaky(h2v.y)};

  // ---- beta logits: acc (in w[]) = h2 @ W3b + b3b; shared W3b loads ----
  {
    const float4* b4 = (const float4*)b3b;
#pragma unroll
    for (int q = 0; q < 4; ++q) {
      float4 b = b4[lane * 4 + q];
      w[4 * q + 0] = f32x2{b.x, b.x};
      w[4 * q + 1] = f32x2{b.y, b.y};
      w[4 * q + 2] = f32x2{b.z, b.z};
      w[4 * q + 3] = f32x2{b.w, b.w};
    }
  }
  for (int m = 0; m < 64; ++m) {
    const f32x2 hm = f32x2{rdlane(h2v.x, m), rdlane(h2v.y, m)};
    const float4* w4 = (const float4*)(W3b + m * N_ORB);
#pragma unroll
    for (int q = 0; q < 4; ++q) {
      float4 wv = w4[lane * 4 + q];
      w[4 * q + 0] = __builtin_elementwise_fma(f32x2{wv.x, wv.x}, hm, w[4 * q + 0]);
      w[4 * q + 1] = __builtin_elementwise_fma(f32x2{wv.y, wv.y}, hm, w[4 * q + 1]);
      w[4 * q + 2] = __builtin_elementwise_fma(f32x2{wv.z, wv.z}, hm, w[4 * q + 2]);
      w[4 * q + 3] = __builtin_elementwise_fma(f32x2{wv.w, wv.w}, hm, w[4 * q + 3]);
    }
  }
  // + base_b + gumbel -> w = exp2(logits * log2e)
  {
    const float4* bb4 = (const float4*)bb;
    const float4* g40 = (const float4*)(g_beta + (size_t)row0 * N_ORB);
    const float4* g41 = (const float4*)(g_beta + (size_t)row1 * N_ORB);
#pragma unroll
    for (int q = 0; q < 4; ++q) {
      float4 b = bb4[lane * 4 + q];
      float4 g0 = g40[lane * 4 + q];
      float4 g1 = g41[lane * 4 + q];
      w[4 * q + 0] = f32x2{
          __builtin_amdgcn_exp2f((w[4 * q + 0].x + b.x + g0.x) * LOG2E),
          __builtin_amdgcn_exp2f((w[4 * q + 0].y + b.x + g1.x) * LOG2E)};
      w[4 * q + 1] = f32x2{
          __builtin_amdgcn_exp2f((w[4 * q + 1].x + b.y + g0.y) * LOG2E),
          __builtin_amdgcn_exp2f((w[4 * q + 1].y + b.y + g1.y) * LOG2E)};
      w[4 * q + 2] = f32x2{
          __builtin_amdgcn_exp2f((w[4 * q + 2].x + b.z + g0.z) * LOG2E),
          __builtin_amdgcn_exp2f((w[4 * q + 2].y + b.z + g1.z) * LOG2E)};
      w[4 * q + 3] = f32x2{
          __builtin_amdgcn_exp2f((w[4 * q + 3].x + b.w + g0.w) * LOG2E),
          __builtin_amdgcn_exp2f((w[4 * q + 3].y + b.w + g1.w) * LOG2E)};
    }
  }
  run_chain2(w, kh);
  unsigned bm0, bm1;
  top32_mask2(kh, lane, bm0, bm1);

  write_half(out + (size_t)row0 * (2 * N_ORB) + N_ORB, bm0, lane);
  if (have1) write_half(out + (size_t)row1 * (2 * N_ORB) + N_ORB, bm1, lane);
}

extern "C" void kernel_launch(void* const* d_in, const int* in_sizes, int n_in,
                              void* d_out, int out_size, void* d_ws, size_t ws_size,
                              hipStream_t stream) {
  const float* ba  = (const float*)d_in[0];
  const float* W1a = (const float*)d_in[1];
  const float* b1a = (const float*)d_in[2];
  const float* W2a = (const float*)d_in[3];
  const float* b2a = (const float*)d_in[4];
  const float* W3a = (const float*)d_in[5];
  const float* b3a = (const float*)d_in[6];
  const float* bb  = (const float*)d_in[7];
  const float* Wc  = (const float*)d_in[8];
  const float* bc  = (const float*)d_in[9];
  const float* W1b = (const float*)d_in[10];
  const float* b1b = (const float*)d_in[11];
  const float* W2b = (const float*)d_in[12];
  const float* b2b = (const float*)d_in[13];
  const float* W3b = (const float*)d_in[14];
  const float* b3b = (const float*)d_in[15];
  const float* ga  = (const float*)d_in[16];
  const float* gbt = (const float*)d_in[17];
  const int B = in_sizes[16] / N_ORB;
  float* ws = (float*)d_ws;

  hipLaunchKernelGGL(pcfs_pre1, dim3(256), dim3(256), 0, stream,
                     ba, W1a, b1a, bb, W1b, ws);
  hipLaunchKernelGGL(pcfs_pre2, dim3(1), dim3(1024), 0, stream,
                     ba, W2a, b2a, W3a, b3a, ws);
  const int pairs = (B + 1) / 2;
  hipLaunchKernelGGL(pcfs_sampler, dim3((pairs + 3) / 4), dim3(256), 0, stream,
                     ws, Wc, bc, W1b, b1b, W2b, b2b, W3b, b3b, bb,
                     ga, gbt, (float*)d_out, B);
}

// Round 10
// 280.409 us; speedup vs baseline: 2.4236x; 1.0158x over previous
//
#include <hip/hip_runtime.h>
#include <hip/hip_bf16.h>
#include <float.h>

#define N_ORB 1024
#define KSEL 32
#define LEAK 0.01f
#define LOG2E 1.4426950408889634f

typedef float f32x2 __attribute__((ext_vector_type(2)));
// NOTE: never write (f32x2)(a, b) — in C++ that's a comma-expr cast that
// SPLATS b. Use f32x2{a, b}.

__device__ __forceinline__ float leaky(float x) { return x >= 0.0f ? x : LEAK * x; }

// ---- DPP helpers ----
template <int CTRL, int RM>
__device__ __forceinline__ int dpp0_i(int v) {  // masked-off rows contribute 0
  return __builtin_amdgcn_update_dpp(0, v, CTRL, RM, 0xF, true);
}
template <int CTRL>
__device__ __forceinline__ float dpp_zero(float v) {
  return __int_as_float(
      __builtin_amdgcn_update_dpp(0, __float_as_int(v), CTRL, 0xF, 0xF, true));
}
__device__ __forceinline__ float rdlane(float v, int l) {
  return __int_as_float(__builtin_amdgcn_readlane(__float_as_int(v), l));
}

// full 64-lane float sum, uniform result
__device__ __forceinline__ float wave_sum64_dpp(float v) {
  v += dpp_zero<0x111>(v);
  v += dpp_zero<0x112>(v);
  v += dpp_zero<0x114>(v);
  v += dpp_zero<0x118>(v);
  v += dpp_zero<0x142>(v);
  v += dpp_zero<0x143>(v);
  return rdlane(v, 63);
}
// full 64-lane int sum, uniform result
__device__ __forceinline__ int wave_isum64(int v) {
  v += dpp0_i<0x111, 0xF>(v);
  v += dpp0_i<0x112, 0xF>(v);
  v += dpp0_i<0x114, 0xF>(v);
  v += dpp0_i<0x118, 0xF>(v);
  v += dpp0_i<0x142, 0xF>(v);
  v += dpp0_i<0x143, 0xF>(v);
  return __builtin_amdgcn_readlane(v, 63);
}
// 64-lane inclusive prefix sum (int), per-lane result
__device__ __forceinline__ int wave_iscan64(int v) {
  v += dpp0_i<0x111, 0xF>(v);
  v += dpp0_i<0x112, 0xF>(v);
  v += dpp0_i<0x114, 0xF>(v);
  v += dpp0_i<0x118, 0xF>(v);
  v += dpp0_i<0x142, 0xA>(v);
  v += dpp0_i<0x143, 0xC>(v);
  return v;
}

// Successive-softmax chain for TWO rows packed in f32x2 (.x=row0,.y=row1),
// multiplicative form (w tracks exp(s)). Element j of a row = lane*16 + j.
// om clamp folds to the VOP3 clamp modifier; equivalent to ref's 1e-20 floor
// at fp32 (khot deltas <= 1e-20, far below any top-32 boundary).
__device__ void run_chain2(f32x2 w[16], f32x2 kh[16]) {
#pragma unroll
  for (int i = 0; i < 16; ++i) kh[i] = f32x2{0.0f, 0.0f};
  const f32x2 onev = f32x2{1.0f, 1.0f};
  const f32x2 zerov = f32x2{0.0f, 0.0f};
  for (int it = 0; it < KSEL; ++it) {
    f32x2 t0 = w[0] + w[1], t1 = w[2] + w[3], t2 = w[4] + w[5], t3 = w[6] + w[7];
    f32x2 t4 = w[8] + w[9], t5 = w[10] + w[11], t6 = w[12] + w[13], t7 = w[14] + w[15];
    t0 += t1; t2 += t3; t4 += t5; t6 += t7;
    t0 += t2; t4 += t6;
    t0 += t4;
    float Z0 = wave_sum64_dpp(t0.x);  // independent of Z1 -> interleaved issue
    float Z1 = wave_sum64_dpp(t0.y);
    Z0 = fmaxf(Z0, 1e-30f);
    Z1 = fmaxf(Z1, 1e-30f);
    float r0 = __builtin_amdgcn_rcpf(Z0);
    float r1 = __builtin_amdgcn_rcpf(Z1);
    float rZ0 = __builtin_fmaf(__builtin_fmaf(-Z0, r0, 1.0f), r0, r0);
    float rZ1 = __builtin_fmaf(__builtin_fmaf(-Z1, r1, 1.0f), r1, r1);
    const f32x2 rZ = f32x2{rZ0, rZ1};
#pragma unroll
    for (int i = 0; i < 16; ++i) {
      kh[i] = __builtin_elementwise_fma(w[i], rZ, kh[i]);
      f32x2 om = __builtin_elementwise_fma(-w[i], rZ, onev);
      om = __builtin_elementwise_min(__builtin_elementwise_max(om, zerov), onev);
      w[i] = w[i] * om;
    }
  }
}

// Tie path for one row (cold). jax stable tie semantics: all >T, then ==T
// in ascending global index ((lane<<4)|slot).
__device__ unsigned tie_mask16(const f32x2 kh[16], bool comp_y, unsigned T,
                               int lane) {
  unsigned gt = 0, eq = 0;
#pragma unroll
  for (int i = 0; i < 16; ++i) {
    const unsigned u = __float_as_uint(comp_y ? kh[i].y : kh[i].x);
    gt |= (u > T ? 1u : 0u) << i;
    eq |= (u == T ? 1u : 0u) << i;
  }
  const int n_gt = wave_isum64(__popc(gt));
  const int m = 32 - n_gt;  // uniform, >= 1 by search invariant
  const int pe = __popc(eq);
  const int be = wave_iscan64(pe) - pe;
  int need = m - be;
  need = need < 0 ? 0 : (need > pe ? pe : need);
  unsigned tk = 0;
  unsigned em = eq;
  for (int guard = 0; guard < 16; ++guard) {
    if (!__any(need > 0)) break;
    if (need > 0) {
      const int bpos = __ffs(em) - 1;
      tk |= 1u << bpos;
      em &= em - 1;
      --need;
    }
  }
  return gt | tk;
}

// Top-32 for both packed rows: joint binary search on the uint views
// (khot >= 0 -> order-isomorphic), ballot+popcll counting, early exit when
// both rows exact. Invariant (r6/r7, field-validated): tie path always
// completes exactly 32.
__device__ void top32_mask2(const f32x2 kh[16], int lane, unsigned& m0,
                            unsigned& m1) {
  unsigned lo0 = 0, lo1 = 0;
  bool ex0 = false, ex1 = false;
  for (int b = 30; b >= 0; --b) {
    const unsigned c0v = lo0 | (1u << b);
    const unsigned c1v = lo1 | (1u << b);
    int c0 = 0, c1 = 0;
#pragma unroll
    for (int i = 0; i < 16; ++i) {
      c0 += __popcll(__ballot(__float_as_uint(kh[i].x) >= c0v));
      c1 += __popcll(__ballot(__float_as_uint(kh[i].y) >= c1v));
    }
    if (!ex0 && c0 >= 32) { lo0 = c0v; ex0 = (c0 == 32); }
    if (!ex1 && c1 >= 32) { lo1 = c1v; ex1 = (c1 == 32); }
    if (ex0 && ex1) break;
  }

  if (ex0) {
    unsigned mk = 0;
#pragma unroll
    for (int i = 0; i < 16; ++i)
      mk |= (__float_as_uint(kh[i].x) >= lo0 ? 1u : 0u) << i;
    m0 = mk;
  } else {
    m0 = tie_mask16(kh, false, lo0, lane);
  }
  if (ex1) {
    unsigned mk = 0;
#pragma unroll
    for (int i = 0; i < 16; ++i)
      mk |= (__float_as_uint(kh[i].y) >= lo1 ? 1u : 0u) << i;
    m1 = mk;
  } else {
    m1 = tie_mask16(kh, true, lo1, lane);
  }
}

// Compact the 32 selected global indices into dst[0..31], ascending order.
__device__ __forceinline__ void compact_idx(unsigned mask, int lane,
                                            int* __restrict__ dst) {
  const int pe = __popc(mask);
  int base = wave_iscan64(pe) - pe;
  unsigned m = mask;
  while (m) {
    const int s = __ffs(m) - 1;
    m &= m - 1;
    dst[base++] = (lane << 4) | s;
  }
}

__device__ __forceinline__ void write_half(float* __restrict__ dst,
                                           unsigned mask, int lane) {
  float4* o4 = (float4*)dst;
#pragma unroll
  for (int q = 0; q < 4; ++q) {
    float4 o;
    o.x = ((mask >> (4 * q + 0)) & 1) ? 1.0f : 0.0f;
    o.y = ((mask >> (4 * q + 1)) & 1) ? 1.0f : 0.0f;
    o.z = ((mask >> (4 * q + 2)) & 1) ? 1.0f : 0.0f;
    o.w = ((mask >> (4 * q + 3)) & 1) ? 1.0f : 0.0f;
    o4[lane * 4 + q] = o;
  }
}

// ---- precompute, stage 1 (grid 256): the two length-1024 dot layers ----
extern "C" __global__ void pcfs_pre1(const float* __restrict__ ba,
                                     const float* __restrict__ W1a,
                                     const float* __restrict__ b1a,
                                     const float* __restrict__ bb,
                                     const float* __restrict__ W1b,
                                     float* __restrict__ ws) {
  const int b = blockIdx.x;
  const int t = threadIdx.x;
  float acc = 0.0f;
  if (b < 128) {
#pragma unroll
    for (int j = t; j < N_ORB; j += 256) acc += ba[j] * W1a[j * 128 + b];
  } else {
    const int n = b - 128;
#pragma unroll
    for (int j = t; j < N_ORB; j += 256) acc += bb[j] * W1b[j * 128 + n];
  }
  __shared__ float red[4];
  float wsum = wave_sum64_dpp(acc);
  if ((t & 63) == 0) red[t >> 6] = wsum;
  __syncthreads();
  if (t == 0) {
    float tot = red[0] + red[1] + red[2] + red[3];
    if (b < 128)
      ws[1152 + b] = leaky(tot + b1a[b]);
    else
      ws[N_ORB + (b - 128)] = tot;
  }
}

// ---- precompute, stage 2 (1 block x 1024): h2 + alpha const logits ----
extern "C" __global__ void pcfs_pre2(const float* __restrict__ ba,
                                     const float* __restrict__ W2a,
                                     const float* __restrict__ b2a,
                                     const float* __restrict__ W3a,
                                     const float* __restrict__ b3a,
                                     float* __restrict__ ws) {
  __shared__ float h1[128];
  __shared__ float h2[64];
  const int t = threadIdx.x;
  if (t < 128) h1[t] = ws[1152 + t];
  __syncthreads();
  if (t < 64) {
    float acc = b2a[t];
#pragma unroll 8
    for (int n = 0; n < 128; ++n) acc += h1[n] * W2a[n * 64 + t];
    h2[t] = leaky(acc);
  }
  __syncthreads();
  float acc = b3a[t];
#pragma unroll 8
  for (int m = 0; m < 64; ++m) acc += h2[m] * W3a[m * N_ORB + t];
  ws[t] = acc + ba[t];  // + base_a
}

// One wave per PAIR of batch rows (.x=row0, .y=row1 in every f32x2).
extern "C" __global__ void __launch_bounds__(256, 4) pcfs_sampler(
    const float* __restrict__ ws, const float* __restrict__ Wc,
    const float* __restrict__ bc, const float* __restrict__ W1b,
    const float* __restrict__ b1b, const float* __restrict__ W2b,
    const float* __restrict__ b2b, const float* __restrict__ W3b,
    const float* __restrict__ b3b, const float* __restrict__ bb,
    const float* __restrict__ g_alpha, const float* __restrict__ g_beta,
    float* __restrict__ out, int B) {
  __shared__ int sidx[4][64];  // per-wave: [0..31]=row0 idxs, [32..63]=row1
  const int wave = threadIdx.x >> 6;
  const int lane = threadIdx.x & 63;
  const int pair = blockIdx.x * 4 + wave;
  const int row0 = pair * 2;
  if (row0 >= B) return;
  const bool have1 = (row0 + 1 < B);
  const int row1 = have1 ? row0 + 1 : row0;

  // ---- prefetch g_beta into registers NOW: these HBM loads drain ~10k
  // cycles later (beta exp2 stage), fully hidden behind the alpha phase ----
  float4 gb0[4], gb1[4];
  {
    const float4* g40 = (const float4*)(g_beta + (size_t)row0 * N_ORB);
    const float4* g41 = (const float4*)(g_beta + (size_t)row1 * N_ORB);
#pragma unroll
    for (int q = 0; q < 4; ++q) {
      gb0[q] = g40[lane * 4 + q];
      gb1[q] = g41[lane * 4 + q];
    }
  }

  f32x2 w[16], kh[16];

  // ---- alpha chains: w = exp2((const_logits + gumbel) * log2e), 2 rows ----
  {
    const float4* c4 = (const float4*)ws;
    const float4* g40 = (const float4*)(g_alpha + (size_t)row0 * N_ORB);
    const float4* g41 = (const float4*)(g_alpha + (size_t)row1 * N_ORB);
#pragma unroll
    for (int q = 0; q < 4; ++q) {
      float4 c = c4[lane * 4 + q];
      float4 g0 = g40[lane * 4 + q];
      float4 g1 = g41[lane * 4 + q];
      w[4 * q + 0] = f32x2{__builtin_amdgcn_exp2f((c.x + g0.x) * LOG2E),
                           __builtin_amdgcn_exp2f((c.x + g1.x) * LOG2E)};
      w[4 * q + 1] = f32x2{__builtin_amdgcn_exp2f((c.y + g0.y) * LOG2E),
                           __builtin_amdgcn_exp2f((c.y + g1.y) * LOG2E)};
      w[4 * q + 2] = f32x2{__builtin_amdgcn_exp2f((c.z + g0.z) * LOG2E),
                           __builtin_amdgcn_exp2f((c.z + g1.z) * LOG2E)};
      w[4 * q + 3] = f32x2{__builtin_amdgcn_exp2f((c.w + g0.w) * LOG2E),
                           __builtin_amdgcn_exp2f((c.w + g1.w) * LOG2E)};
    }
  }
  run_chain2(w, kh);
  unsigned am0, am1;
  top32_mask2(kh, lane, am0, am1);

  // write alpha halves (hard config: exact 0/1)
  write_half(out + (size_t)row0 * (2 * N_ORB), am0, lane);
  if (have1) write_half(out + (size_t)row1 * (2 * N_ORB), am1, lane);

  // ---- ctx = alpha_config @ Wc + bc, per row (LDS compact + fixed trip) ----
  compact_idx(am0, lane, &sidx[wave][0]);
  compact_idx(am1, lane, &sidx[wave][32]);
  const int vi0 = sidx[wave][lane & 31];
  const int vi1 = sidx[wave][32 + (lane & 31)];
  const float bcv = bc[lane & 31];
  float ctx0 = bcv, ctx1 = bcv;
#pragma unroll
  for (int r = 0; r < 32; ++r) {
    const int i0 = __builtin_amdgcn_readlane(vi0, r);  // uniform
    const int i1 = __builtin_amdgcn_readlane(vi1, r);
    ctx0 += Wc[i0 * 32 + (lane & 31)];
    ctx1 += Wc[i1 * 32 + (lane & 31)];
  }

  // ---- h1 = leaky(base_b@W1b[0:1024] + ctx@W1b[1024:1056] + b1b) ----
  f32x2 h1a, h1b_;
  {
    const float ia = b1b[lane] + ws[N_ORB + lane];
    const float ib = b1b[lane + 64] + ws[N_ORB + lane + 64];
    h1a = f32x2{ia, ia};
    h1b_ = f32x2{ib, ib};
  }
#pragma unroll 4
  for (int c = 0; c < 32; ++c) {
    const f32x2 cv = f32x2{rdlane(ctx0, c), rdlane(ctx1, c)};
    const float* wr = W1b + (size_t)(N_ORB + c) * 128;
    const float wa = wr[lane], wb = wr[lane + 64];
    h1a = __builtin_elementwise_fma(f32x2{wa, wa}, cv, h1a);
    h1b_ = __builtin_elementwise_fma(f32x2{wb, wb}, cv, h1b_);
  }
  h1a = f32x2{leaky(h1a.x), leaky(h1a.y)};
  h1b_ = f32x2{leaky(h1b_.x), leaky(h1b_.y)};

  // ---- h2 = leaky(h1 @ W2b + b2b): 4 partial accumulators (32-deep
  // chains instead of 128-deep) ----
  f32x2 h2p0, h2p1, h2p2, h2p3;
  {
    const float i2 = b2b[lane];
    h2p0 = f32x2{i2, i2};
    h2p1 = f32x2{0.0f, 0.0f};
    h2p2 = f32x2{0.0f, 0.0f};
    h2p3 = f32x2{0.0f, 0.0f};
  }
#pragma unroll 4
  for (int n = 0; n < 64; n += 4) {
    const f32x2 v0 = f32x2{rdlane(h1a.x, n + 0), rdlane(h1a.y, n + 0)};
    const f32x2 v1 = f32x2{rdlane(h1a.x, n + 1), rdlane(h1a.y, n + 1)};
    const f32x2 v2 = f32x2{rdlane(h1a.x, n + 2), rdlane(h1a.y, n + 2)};
    const f32x2 v3 = f32x2{rdlane(h1a.x, n + 3), rdlane(h1a.y, n + 3)};
    const float w0 = W2b[(n + 0) * 64 + lane];
    const float w1 = W2b[(n + 1) * 64 + lane];
    const float w2 = W2b[(n + 2) * 64 + lane];
    const float w3 = W2b[(n + 3) * 64 + lane];
    h2p0 = __builtin_elementwise_fma(f32x2{w0, w0}, v0, h2p0);
    h2p1 = __builtin_elementwise_fma(f32x2{w1, w1}, v1, h2p1);
    h2p2 = __builtin_elementwise_fma(f32x2{w2, w2}, v2, h2p2);
    h2p3 = __builtin_elementwise_fma(f32x2{w3, w3}, v3, h2p3);
  }
#pragma unroll 4
  for (int n = 0; n < 64; n += 4) {
    const f32x2 v0 = f32x2{rdlane(h1b_.x, n + 0), rdlane(h1b_.y, n + 0)};
    const f32x2 v1 = f32x2{rdlane(h1b_.x, n + 1), rdlane(h1b_.y, n + 1)};
    const f32x2 v2 = f32x2{rdlane(h1b_.x, n + 2), rdlane(h1b_.y, n + 2)};
    const f32x2 v3 = f32x2{rdlane(h1b_.x, n + 3), rdlane(h1b_.y, n + 3)};
    const float w0 = W2b[(n + 64 + 0) * 64 + lane];
    const float w1 = W2b[(n + 64 + 1) * 64 + lane];
    const float w2 = W2b[(n + 64 + 2) * 64 + lane];
    const float w3 = W2b[(n + 64 + 3) * 64 + lane];
    h2p0 = __builtin_elementwise_fma(f32x2{w0, w0}, v0, h2p0);
    h2p1 = __builtin_elementwise_fma(f32x2{w1, w1}, v1, h2p1);
    h2p2 = __builtin_elementwise_fma(f32x2{w2, w2}, v2, h2p2);
    h2p3 = __builtin_elementwise_fma(f32x2{w3, w3}, v3, h2p3);
  }
  f32x2 h2v = (h2p0 + h2p1) + (h2p2 + h2p3);
  h2v = f32x2{leaky(h2v.x), leaky(h2v.y)};

  // ---- beta logits: acc (in w[]) = h2 @ W3b + b3b; shared W3b loads,
  // unrolled x4 so 16 float4 loads pipeline per group ----
  {
    const float4* b4 = (const float4*)b3b;
#pragma unroll
    for (int q = 0; q < 4; ++q) {
      float4 b = b4[lane * 4 + q];
      w[4 * q + 0] = f32x2{b.x, b.x};
      w[4 * q + 1] = f32x2{b.y, b.y};
      w[4 * q + 2] = f32x2{b.z, b.z};
      w[4 * q + 3] = f32x2{b.w, b.w};
    }
  }
#pragma unroll 4
  for (int m = 0; m < 64; ++m) {
    const f32x2 hm = f32x2{rdlane(h2v.x, m), rdlane(h2v.y, m)};
    const float4* w4 = (const float4*)(W3b + m * N_ORB);
#pragma unroll
    for (int q = 0; q < 4; ++q) {
      float4 wv = w4[lane * 4 + q];
      w[4 * q + 0] = __builtin_elementwise_fma(f32x2{wv.x, wv.x}, hm, w[4 * q + 0]);
      w[4 * q + 1] = __builtin_elementwise_fma(f32x2{wv.y, wv.y}, hm, w[4 * q + 1]);
      w[4 * q + 2] = __builtin_elementwise_fma(f32x2{wv.z, wv.z}, hm, w[4 * q + 2]);
      w[4 * q + 3] = __builtin_elementwise_fma(f32x2{wv.w, wv.w}, hm, w[4 * q + 3]);
    }
  }
  // + base_b + gumbel (prefetched) -> w = exp2(logits * log2e)
  {
    const float4* bb4 = (const float4*)bb;
#pragma unroll
    for (int q = 0; q < 4; ++q) {
      float4 b = bb4[lane * 4 + q];
      const float4 g0 = gb0[q];
      const float4 g1 = gb1[q];
      w[4 * q + 0] = f32x2{
          __builtin_amdgcn_exp2f((w[4 * q + 0].x + b.x + g0.x) * LOG2E),
          __builtin_amdgcn_exp2f((w[4 * q + 0].y + b.x + g1.x) * LOG2E)};
      w[4 * q + 1] = f32x2{
          __builtin_amdgcn_exp2f((w[4 * q + 1].x + b.y + g0.y) * LOG2E),
          __builtin_amdgcn_exp2f((w[4 * q + 1].y + b.y + g1.y) * LOG2E)};
      w[4 * q + 2] = f32x2{
          __builtin_amdgcn_exp2f((w[4 * q + 2].x + b.z + g0.z) * LOG2E),
          __builtin_amdgcn_exp2f((w[4 * q + 2].y + b.z + g1.z) * LOG2E)};
      w[4 * q + 3] = f32x2{
          __builtin_amdgcn_exp2f((w[4 * q + 3].x + b.w + g0.w) * LOG2E),
          __builtin_amdgcn_exp2f((w[4 * q + 3].y + b.w + g1.w) * LOG2E)};
    }
  }
  run_chain2(w, kh);
  unsigned bm0, bm1;
  top32_mask2(kh, lane, bm0, bm1);

  write_half(out + (size_t)row0 * (2 * N_ORB) + N_ORB, bm0, lane);
  if (have1) write_half(out + (size_t)row1 * (2 * N_ORB) + N_ORB, bm1, lane);
}

extern "C" void kernel_launch(void* const* d_in, const int* in_sizes, int n_in,
                              void* d_out, int out_size, void* d_ws, size_t ws_size,
                              hipStream_t stream) {
  const float* ba  = (const float*)d_in[0];
  const float* W1a = (const float*)d_in[1];
  const float* b1a = (const float*)d_in[2];
  const float* W2a = (const float*)d_in[3];
  const float* b2a = (const float*)d_in[4];
  const float* W3a = (const float*)d_in[5];
  const float* b3a = (const float*)d_in[6];
  const float* bb  = (const float*)d_in[7];
  const float* Wc  = (const float*)d_in[8];
  const float* bc  = (const float*)d_in[9];
  const float* W1b = (const float*)d_in[10];
  const float* b1b = (const float*)d_in[11];
  const float* W2b = (const float*)d_in[12];
  const float* b2b = (const float*)d_in[13];
  const float* W3b = (const float*)d_in[14];
  const float* b3b = (const float*)d_in[15];
  const float* ga  = (const float*)d_in[16];
  const float* gbt = (const float*)d_in[17];
  const int B = in_sizes[16] / N_ORB;
  float* ws = (float*)d_ws;

  hipLaunchKernelGGL(pcfs_pre1, dim3(256), dim3(256), 0, stream,
                     ba, W1a, b1a, bb, W1b, ws);
  hipLaunchKernelGGL(pcfs_pre2, dim3(1), dim3(1024), 0, stream,
                     ba, W2a, b2a, W3a, b3a, ws);
  const int pairs = (B + 1) / 2;
  hipLaunchKernelGGL(pcfs_sampler, dim3((pairs + 3) / 4), dim3(256), 0, stream,
                     ws, Wc, bc, W1b, b1b, W2b, b2b, W3b, b3b, bb,
                     ga, gbt, (float*)d_out, B);
}